// Round 9
// baseline (402.114 us; speedup 1.0000x reference)
//
#include <hip/hip_runtime.h>
#include <hip/hip_bf16.h>

typedef __hip_bfloat16 bf16;
typedef __attribute__((ext_vector_type(8))) short s16x8;
typedef __attribute__((ext_vector_type(4))) float f32x4;

#define DEV __device__ __forceinline__

DEV float b2f(bf16 v){ return __bfloat162float(v); }
DEV ushort f2bf(float f){ bf16 h = __float2bfloat16(f); return *reinterpret_cast<ushort*>(&h); }
DEV float bf2f(ushort u){ bf16 h; *reinterpret_cast<ushort*>(&h) = u; return __bfloat162float(h); }

constexpr int NPIX = 1024;
constexpr float EPSF = 1e-5f;
constexpr float LAMBDA_INIT_F = 0.3555090675909693f;
constexpr float ONE_M_LI     = 0.6444909324090307f;
constexpr float ATT_SCALE    = 0.17677669529663687f;

// workspace offsets (floats)
constexpr size_t OFF_XBUF  = 0;         // f32 [4][1024][256] residual, channel-last
constexpr size_t OFF_PARM  = 1048576;   // 17480 small params
constexpr size_t OFF_WBF   = 2120448;   // bf16 weights (1048576 ushorts)
constexpr size_t OFF_QT    = 2644736;   // QT/KT bf16 [2][4][8][1024][64]
constexpr size_t OFF_V16   = 4741888;   // V bf16 [4][512][1024]
constexpr size_t OFF_ATT   = 5790464;   // att bf16 [4][1024][512]; later chaout bf16 [4][1024][256]
constexpr size_t OFF_BUF1  = 6839040;   // f32 [4][768][1024] qkv / ffn1 (channel-first)
constexpr size_t OFF_BUF2  = 9984768;   // f32 dw / gconv out (channel-first)
constexpr size_t OFF_STATS = 13425408;  // 3 x [sum 4096 | sq 4096]
constexpr size_t OFF_EFF   = 13449984;  // folded params (2560) + lam(8)
constexpr size_t OFF_FLAG  = 13452608;

struct PackArgs { const void* p[34]; };

// ---------------- dtype detect ----------------
__global__ __launch_bounds__(256) void detect_kernel(const void* __restrict__ x, int* __restrict__ flag){
  __shared__ int sh;
  if (threadIdx.x == 0) sh = 0;
  __syncthreads();
  const bf16* h = (const bf16*)x;
  int local = 0;
  for (int i = threadIdx.x; i < 4096; i += 256){
    float v = b2f(h[i]);
    if (!(fabsf(v) <= 1e6f)) local = 1;
  }
  if (local) atomicOr(&sh, 1);
  __syncthreads();
  if (threadIdx.x == 0) *flag = sh;
}

DEV float rdin(const PackArgs& a, int i, int idx, int flag){
  return flag ? ((const float*)a.p[i])[idx] : b2f(((const bf16*)a.p[i])[idx]);
}

// ---------------- prep: parm pack + Wbf pack + eff/lam + zero stats ----------------
__global__ __launch_bounds__(256) void prep_all_kernel(PackArgs args, const int* __restrict__ flagp,
    float* __restrict__ parm, ushort* __restrict__ W, float* __restrict__ eff, float* __restrict__ stats){
  const int t = threadIdx.x;
  const int blk = blockIdx.x;
  const int flag = *flagp;
  if (blk < 69){
    const int g = blk*256 + t;
    if (g >= 17480) return;
    int src, loc;
    if      (g < 64)    { src = 10; loc = g; }
    else if (g < 72)    { src = 14; loc = g - 64; }
    else if (g < 6984)  { src = 16; loc = g - 72; }
    else if (g < 7496)  { src = 25; loc = g - 6984; }
    else if (g < 16712) { src = 30; loc = g - 7496; }
    else if (g < 17224) { src = 31; loc = g - 16712; }
    else                { src = 33; loc = g - 17224; }
    parm[g] = rdin(args, src, loc, flag);
  } else if (blk < 1093){
    const int g = (blk - 69)*1024 + t*4;     // < 1048576
    int src, loc;
    if      (g <  131072){ src = 3;  loc = g; }
    else if (g <  262144){ src = 4;  loc = g - 131072; }
    else if (g <  393216){ src = 5;  loc = g - 262144; }
    else if (g <  589824){ src = 15; loc = g - 393216; }
    else if (g <  720896){ src = 11; loc = g - 589824; }
    else if (g <  786432){ src = 17; loc = g - 720896; }
    else if (g <  917504){ src = 24; loc = g - 786432; }
    else                 { src = 32; loc = g - 917504; }
    ushort4 o;
    if (flag){
      const float4 v = *(const float4*)((const float*)args.p[src] + loc);
      o = make_ushort4(f2bf(v.x), f2bf(v.y), f2bf(v.z), f2bf(v.w));
    } else {
      o = *(const ushort4*)((const ushort*)args.p[src] + loc);
    }
    *(ushort4*)&W[g] = o;
  } else if (blk == 1093){
    eff[t]      = rdin(args,1,t,flag);  eff[256+t] = rdin(args,2,t,flag);
    eff[512+t]  = rdin(args,12,t,flag); eff[768+t] = rdin(args,13,t,flag);
    const float s1 = rdin(args,20,t,flag) * rsqrtf(rdin(args,23,t,flag) + EPSF);
    eff[1024+t] = rdin(args,18,t,flag) * s1;
    eff[1280+t] = (rdin(args,19,t,flag) - rdin(args,22,t,flag)) * s1 + rdin(args,21,t,flag);
    for (int c = t; c < 512; c += 256){
      const float sc = rdin(args,26,c,flag) * rsqrtf(rdin(args,29,c,flag) + EPSF);
      eff[1536+c] = sc;
      eff[2048+c] = rdin(args,27,c,flag) - rdin(args,28,c,flag)*sc;
    }
    if (t < 8){
      float e1 = 0.f, e2 = 0.f;
      for (int i = 0; i < 32; i++){
        e1 += rdin(args,6,t*32+i,flag) * rdin(args,7,t*32+i,flag);
        e2 += rdin(args,8,t*32+i,flag) * rdin(args,9,t*32+i,flag);
      }
      eff[2560+t] = __expf(e1) - __expf(e2) + LAMBDA_INIT_F;
    }
  } else {
    // 1094..1117: zero all 3 stats sections (24576 floats)
    const int i = (blk - 1094)*1024 + t*4;
    *(float4*)&stats[i] = make_float4(0.f,0.f,0.f,0.f);
  }
}

// ---------------- xpose: x [b][c][n] -> xbuf [b][n][c] f32 + LN1 raw stats ----------------
__global__ __launch_bounds__(256) void xpose_kernel(const void* __restrict__ xin,
    const int* __restrict__ flagp, float* __restrict__ xb, float* __restrict__ stats){
  __shared__ float T[64][68];
  __shared__ float psum[64][4], psq[64][4];
  const int t = threadIdx.x;
  const int nt = blockIdx.x*64, ct = blockIdx.y*64, b = blockIdx.z;
  const int flag = *flagp;
  { const int c_ = t >> 2, nq = t & 3;
    const size_t base = ((size_t)b*256 + ct + c_)*1024 + nt + nq*16;
    float tmp[16];
    if (flag){
      #pragma unroll
      for (int j = 0; j < 4; j++){
        const float4 v = *(const float4*)((const float*)xin + base + j*4);
        tmp[j*4+0]=v.x; tmp[j*4+1]=v.y; tmp[j*4+2]=v.z; tmp[j*4+3]=v.w;
      }
    } else {
      const ushort* xh = (const ushort*)xin + base;
      #pragma unroll
      for (int j = 0; j < 2; j++){
        uint4 u = *(const uint4*)(xh + j*8);
        const ushort* us = (const ushort*)&u;
        #pragma unroll
        for (int k = 0; k < 8; k++) tmp[j*8+k] = bf2f(us[k]);
      }
    }
    #pragma unroll
    for (int j = 0; j < 4; j++)
      *(float4*)&T[c_][nq*16 + j*4] = make_float4(tmp[j*4],tmp[j*4+1],tmp[j*4+2],tmp[j*4+3]);
  }
  __syncthreads();
  { const int n_ = t >> 2, cq = t & 3;
    float s = 0.f, q = 0.f;
    float tmp[16];
    #pragma unroll
    for (int i = 0; i < 16; i++){
      const float v = T[cq*16 + i][n_];
      tmp[i] = v; s += v; q += v*v;
    }
    #pragma unroll
    for (int j = 0; j < 4; j++)
      *(float4*)&xb[((size_t)b*NPIX + nt + n_)*256 + ct + cq*16 + j*4] =
          make_float4(tmp[j*4],tmp[j*4+1],tmp[j*4+2],tmp[j*4+3]);
    psum[n_][cq] = s; psq[n_][cq] = q;
  }
  __syncthreads();
  if (t < 64){
    const float s = psum[t][0]+psum[t][1]+psum[t][2]+psum[t][3];
    const float q = psq[t][0]+psq[t][1]+psq[t][2]+psq[t][3];
    atomicAdd(&stats[(size_t)b*NPIX + nt + t], s);
    atomicAdd(&stats[4096 + (size_t)b*NPIX + nt + t], q);
  }
}

// ---------------- unified MFMA GEMM ----------------
// IN: 0 = f32 [b][n][Cin] + LN(raw stats); 1 = f32 [b][c][n] plain; 2 = bf16 [b][n][Cin]
// EPI: 0 = QKV special; 1 = f32 [n][c] +res (opt STATS); 2 = f32 [c][n] (+bias)(+bn2); 3 = final d_out
template<int INM, int EPIM, bool BIAS, bool BN2F, bool STATS>
__global__ __launch_bounds__(256) void gemm_kernel(
    const float* __restrict__ Xf, const ushort* __restrict__ Xb, const ushort* __restrict__ W,
    const float* __restrict__ bias, const float* __restrict__ mu, const float* __restrict__ rstd,
    const float* __restrict__ effw, const float* __restrict__ effb,
    const float* __restrict__ s2, const float* __restrict__ t2,
    const float* __restrict__ res, void* __restrict__ out,
    ushort* __restrict__ qt, ushort* __restrict__ v16,
    float* __restrict__ gstats,
    int Cin, const int* __restrict__ flag)
{
  __shared__ ushort Xt[64][72];
  const int t = threadIdx.x;
  const int nb = blockIdx.x*64, ob = blockIdx.y*64, b = blockIdx.z;
  const int lane = t & 63, w = t >> 6;
  const int wR = w >> 1, wC = w & 1;
  const int l15 = lane & 15, g = lane >> 4;
  const int tn = t & 63, tc4 = t >> 6;
  const f32x4 z4 = {0.f,0.f,0.f,0.f};
  f32x4 acc[2][2] = {{z4,z4},{z4,z4}};

  float m_ = 0.f, r_ = 1.f;
  if (INM == 0){
    const int n_ = t >> 2;
    const float sv = mu[(size_t)b*NPIX + nb + n_];
    const float qv = rstd[(size_t)b*NPIX + nb + n_];
    m_ = sv * (1.f/256.f);
    r_ = rsqrtf(fmaxf(qv*(1.f/256.f) - m_*m_, 0.f) + EPSF);
  }

  for (int kb = 0; kb < Cin; kb += 64){
    if (INM == 2){
      const ushort* src = Xb + ((size_t)b*NPIX + nb + tn)*Cin + kb + tc4*16;
      *(uint4*)&Xt[tn][tc4*16]   = *(const uint4*)src;
      *(uint4*)&Xt[tn][tc4*16+8] = *(const uint4*)(src+8);
    } else if (INM == 0){
      const int n_ = t >> 2, cq = t & 3;
      const float* src = Xf + ((size_t)b*NPIX + nb + n_)*Cin + kb + cq*16;
      float f[16];
      #pragma unroll
      for (int j = 0; j < 4; j++){
        const float4 v = *(const float4*)(src + j*4);
        f[j*4+0]=v.x; f[j*4+1]=v.y; f[j*4+2]=v.z; f[j*4+3]=v.w;
      }
      ushort tmp[16];
      #pragma unroll
      for (int i = 0; i < 16; i++){
        const int c = kb + cq*16 + i;
        tmp[i] = f2bf((f[i] - m_)*r_*effw[c] + effb[c]);
      }
      *(uint4*)&Xt[n_][cq*16]   = *(uint4*)&tmp[0];
      *(uint4*)&Xt[n_][cq*16+8] = *(uint4*)&tmp[8];
    } else {
      ushort tmp[16];
      #pragma unroll
      for (int i = 0; i < 16; i++){
        const int c = kb + tc4*16 + i;
        tmp[i] = f2bf(Xf[((size_t)b*Cin + c)*NPIX + nb + tn]);
      }
      *(uint4*)&Xt[tn][tc4*16]   = *(uint4*)&tmp[0];
      *(uint4*)&Xt[tn][tc4*16+8] = *(uint4*)&tmp[8];
    }
    __syncthreads();
    #pragma unroll
    for (int ks = 0; ks < 2; ks++){
      const s16x8 a0 = *(const s16x8*)&W[(size_t)(ob + wR*32 + l15)*Cin + kb + ks*32 + g*8];
      const s16x8 a1 = *(const s16x8*)&W[(size_t)(ob + wR*32 + 16 + l15)*Cin + kb + ks*32 + g*8];
      const s16x8 b0 = *(const s16x8*)&Xt[wC*32 + l15][ks*32 + g*8];
      const s16x8 b1 = *(const s16x8*)&Xt[wC*32 + 16 + l15][ks*32 + g*8];
      acc[0][0] = __builtin_amdgcn_mfma_f32_16x16x32_bf16(a0, b0, acc[0][0], 0,0,0);
      acc[0][1] = __builtin_amdgcn_mfma_f32_16x16x32_bf16(a0, b1, acc[0][1], 0,0,0);
      acc[1][0] = __builtin_amdgcn_mfma_f32_16x16x32_bf16(a1, b0, acc[1][0], 0,0,0);
      acc[1][1] = __builtin_amdgcn_mfma_f32_16x16x32_bf16(a1, b1, acc[1][1], 0,0,0);
    }
    __syncthreads();
  }

  const int Cout = gridDim.y*64;
  const int fl = (EPIM == 3) ? *flag : 0;
  float sst[2] = {0.f, 0.f}, qst[2] = {0.f, 0.f};
  #pragma unroll
  for (int fr = 0; fr < 2; fr++){
    #pragma unroll
    for (int fc = 0; fc < 2; fc++){
      const int o = ob + wR*32 + fr*16 + 4*g;
      const int n = nb + wC*32 + fc*16 + l15;
      const f32x4 v = acc[fr][fc];
      if (EPIM == 0){
        if (ob < 1024){
          const int qk = o >> 9, h = (o >> 6) & 7, d = o & 63;
          ushort4 pk = make_ushort4(f2bf(v[0]), f2bf(v[1]), f2bf(v[2]), f2bf(v[3]));
          ushort* dst = qt + ((((size_t)qk*4 + b)*8 + h)*NPIX + n)*64 + d;
          *(ushort4*)dst = pk;
        } else {
          const int c = o - 1024;
          #pragma unroll
          for (int r = 0; r < 4; r++)
            v16[((size_t)b*512 + c + r)*NPIX + n] = f2bf(v[r]);
        }
      } else if (EPIM == 1){
        const size_t row = ((size_t)b*NPIX + n)*Cout + o;
        const float4 r4 = *(const float4*)&res[row];
        float vals[4];
        #pragma unroll
        for (int r = 0; r < 4; r++){
          float val = v[r];
          if (BIAS) val += bias[o+r];
          if (BN2F) val = val*s2[o+r] + t2[o+r];
          vals[r] = val + ((const float*)&r4)[r];
        }
        *(float4*)&((float*)out)[row] = make_float4(vals[0],vals[1],vals[2],vals[3]);
        if (STATS){
          sst[fc] += vals[0]+vals[1]+vals[2]+vals[3];
          qst[fc] += vals[0]*vals[0]+vals[1]*vals[1]+vals[2]*vals[2]+vals[3]*vals[3];
        }
      } else if (EPIM == 2){
        #pragma unroll
        for (int r = 0; r < 4; r++){
          float val = v[r];
          if (BIAS) val += bias[o + r];
          if (BN2F) val = val*s2[o+r] + t2[o+r];
          ((float*)out)[((size_t)b*Cout + o + r)*NPIX + n] = val;
        }
      } else {
        const float4 r4 = *(const float4*)&res[((size_t)b*NPIX + n)*256 + o];
        #pragma unroll
        for (int r = 0; r < 4; r++){
          float val = v[r] + ((const float*)&r4)[r];
          if (BIAS) val += bias[o+r];
          const size_t row = ((size_t)b*256 + o + r)*NPIX + n;
          if (fl) ((float*)out)[row] = val;
          else    ((ushort*)out)[row] = f2bf(val);
        }
      }
    }
  }
  if (STATS){
    float* sacc = (float*)&Xt[0][0];
    if (t < 128) sacc[t] = 0.f;
    __syncthreads();
    #pragma unroll
    for (int fc = 0; fc < 2; fc++){
      const int nl = wC*32 + fc*16 + l15;
      atomicAdd(&sacc[nl*2+0], sst[fc]);
      atomicAdd(&sacc[nl*2+1], qst[fc]);
    }
    __syncthreads();
    if (t < 64){
      atomicAdd(&gstats[(size_t)b*NPIX + nb + t],        sacc[t*2+0]);
      atomicAdd(&gstats[4096 + (size_t)b*NPIX + nb + t], sacc[t*2+1]);
    }
  }
}

// ---------------- MFMA differential attention, LDS-staged K/V ----------------
__global__ __launch_bounds__(256) void attn_kernel(
    const ushort* __restrict__ QT, const ushort* __restrict__ V16,
    const float* __restrict__ rms, const float* __restrict__ lamArr,
    ushort* __restrict__ att)
{
  __shared__ ushort Ks[2][4096];
  __shared__ ushort Vs[2][4096];
  const int t = threadIdx.x;
  const int lane = t & 63, w = t >> 6;
  const int l15 = lane & 15, g = lane >> 4;
  const int qt = blockIdx.x, h = blockIdx.y, b = blockIdx.z;
  const int qsub = qt*64 + w*16;
  const ushort* Qb = QT + ((size_t)b*8 + h)*NPIX*64;
  const ushort* Kb = QT + ((size_t)(4 + b)*8 + h)*NPIX*64;
  const ushort* Vb = V16 + ((size_t)b*512 + h*64)*NPIX;

  const int c0row = t >> 3, c0col = t & 7;
  const int c1row = (t + 256) >> 3, c1col = t & 7;
  const int sw0 = (c0col ^ (c0row & 7))*8;
  const int sw1 = (c1col ^ (c1row & 7))*8;

  s16x8 bq[2];
  #pragma unroll
  for (int hx = 0; hx < 2; hx++)
    bq[hx] = *(const s16x8*)&Qb[(size_t)(qsub + l15)*64 + 32*hx + 8*g];
  const float lam = lamArr[h];

  const f32x4 z4 = {0.f,0.f,0.f,0.f};
  f32x4 o0[4] = {z4,z4,z4,z4};
  f32x4 o1[4] = {z4,z4,z4,z4};
  float z[2] = {0.f, 0.f};

  uint4 kra = *(const uint4*)&Kb[(size_t)c0row*64 + c0col*8];
  uint4 krb = *(const uint4*)&Kb[(size_t)c1row*64 + c1col*8];
  uint4 vra = *(const uint4*)&Vb[(size_t)c0row*NPIX + c0col*8];
  uint4 vrb = *(const uint4*)&Vb[(size_t)c1row*NPIX + c1col*8];
  *(uint4*)&Ks[0][c0row*64 + sw0] = kra;
  *(uint4*)&Ks[0][c1row*64 + sw1] = krb;
  *(uint4*)&Vs[0][c0row*64 + sw0] = vra;
  *(uint4*)&Vs[0][c1row*64 + sw1] = vrb;
  kra = *(const uint4*)&Kb[(size_t)(64 + c0row)*64 + c0col*8];
  krb = *(const uint4*)&Kb[(size_t)(64 + c1row)*64 + c1col*8];
  vra = *(const uint4*)&Vb[(size_t)c0row*NPIX + 64 + c0col*8];
  vrb = *(const uint4*)&Vb[(size_t)c1row*NPIX + 64 + c1col*8];
  __syncthreads();

  #pragma unroll 1
  for (int it = 0; it < 16; it++){
    const int cur = it & 1;
    const ushort* Kc = &Ks[cur][0];
    const ushort* Vc = &Vs[cur][0];

    f32x4 s[2][4];
    #pragma unroll
    for (int fr = 0; fr < 4; fr++){
      const int row = fr*16 + l15;
      const int rx = (row & 7)*8;
      #pragma unroll
      for (int hx = 0; hx < 2; hx++){
        const s16x8 ak = *(const s16x8*)&Kc[row*64 + ((hx*32 + 8*g) ^ rx)];
        s[hx][fr] = __builtin_amdgcn_mfma_f32_16x16x32_bf16(ak, bq[hx], z4, 0,0,0);
      }
    }
    s16x8 pa[2][2];
    #pragma unroll
    for (int hx = 0; hx < 2; hx++){
      #pragma unroll
      for (int ms = 0; ms < 2; ms++){
        ushort tmp[8];
        #pragma unroll
        for (int fr2 = 0; fr2 < 2; fr2++)
          #pragma unroll
          for (int r = 0; r < 4; r++){
            const float e = __expf(s[hx][ms*2 + fr2][r] * ATT_SCALE);
            z[hx] += e;
            tmp[fr2*4 + r] = f2bf(e);
          }
        pa[hx][ms] = *(s16x8*)tmp;
      }
    }
    __builtin_amdgcn_s_setprio(1);
    #pragma unroll
    for (int ms = 0; ms < 2; ms++){
      #pragma unroll
      for (int dc = 0; dc < 4; dc++){
        const int row = dc*16 + l15;
        const int r7 = row & 7;
        const int elo = ms*32 + 4*g;
        const int eloswz = ((((elo >> 3) ^ r7) << 3) | (elo & 7));
        const int ehi = elo + 16;
        const int ehiswz = ((((ehi >> 3) ^ r7) << 3) | (ehi & 7));
        const uint2 lo = *(const uint2*)&Vc[row*64 + eloswz];
        const uint2 hi = *(const uint2*)&Vc[row*64 + ehiswz];
        union { uint u[4]; s16x8 v; } bv;
        bv.u[0] = lo.x; bv.u[1] = lo.y; bv.u[2] = hi.x; bv.u[3] = hi.y;
        o0[dc] = __builtin_amdgcn_mfma_f32_16x16x32_bf16(pa[0][ms], bv.v, o0[dc], 0,0,0);
        o1[dc] = __builtin_amdgcn_mfma_f32_16x16x32_bf16(pa[1][ms], bv.v, o1[dc], 0,0,0);
      }
    }
    __builtin_amdgcn_s_setprio(0);

    if (it < 15){
      const int nxt = cur ^ 1;
      *(uint4*)&Ks[nxt][c0row*64 + sw0] = kra;
      *(uint4*)&Ks[nxt][c1row*64 + sw1] = krb;
      *(uint4*)&Vs[nxt][c0row*64 + sw0] = vra;
      *(uint4*)&Vs[nxt][c1row*64 + sw1] = vrb;
      if (it < 14){
        const int m0 = (it + 2)*64;
        kra = *(const uint4*)&Kb[(size_t)(m0 + c0row)*64 + c0col*8];
        krb = *(const uint4*)&Kb[(size_t)(m0 + c1row)*64 + c1col*8];
        vra = *(const uint4*)&Vb[(size_t)c0row*NPIX + m0 + c0col*8];
        vrb = *(const uint4*)&Vb[(size_t)c1row*NPIX + m0 + c1col*8];
      }
    }
    __syncthreads();
  }

  #pragma unroll
  for (int hx = 0; hx < 2; hx++){
    z[hx] += __shfl_xor(z[hx], 16);
    z[hx] += __shfl_xor(z[hx], 32);
  }
  float zi0[4], zi1[4];
  #pragma unroll
  for (int r = 0; r < 4; r++){
    zi0[r] = 1.f / __shfl(z[0], 4*g + r);
    zi1[r] = 1.f / __shfl(z[1], 4*g + r);
  }
  float val[4][4];
  float ss[4] = {0.f,0.f,0.f,0.f};
  #pragma unroll
  for (int dc = 0; dc < 4; dc++)
    #pragma unroll
    for (int r = 0; r < 4; r++){
      const float vv = o0[dc][r]*zi0[r] - lam*o1[dc][r]*zi1[r];
      val[dc][r] = vv; ss[r] += vv*vv;
    }
  #pragma unroll
  for (int r = 0; r < 4; r++){
    ss[r] += __shfl_xor(ss[r], 1);
    ss[r] += __shfl_xor(ss[r], 2);
    ss[r] += __shfl_xor(ss[r], 4);
    ss[r] += __shfl_xor(ss[r], 8);
  }
  float rinv[4];
  #pragma unroll
  for (int r = 0; r < 4; r++) rinv[r] = ONE_M_LI * rsqrtf(ss[r]*(1.f/64.f) + EPSF);
  #pragma unroll
  for (int dc = 0; dc < 4; dc++){
    const float rs = rms[dc*16 + l15];
    #pragma unroll
    for (int r = 0; r < 4; r++){
      const int n = qsub + 4*g + r;
      att[((size_t)b*NPIX + n)*512 + h*64 + dc*16 + l15] = f2bf(val[dc][r]*rinv[r]*rs);
    }
  }
}

// ---------------- fused depthwise 3x3 + L2-norm (block = plane) ----------------
__global__ __launch_bounds__(256) void dwl2_kernel(const float* __restrict__ in,
    const float* __restrict__ wdw, float* __restrict__ out){
  __shared__ float tile[1024];
  __shared__ float wsum[4];
  const int p = blockIdx.x;                 // b*768 + c
  const int c = p % 768;
  const int t = threadIdx.x;
  const float* ip = in + (size_t)p*1024;
  *(float4*)&tile[t*4] = *(const float4*)&ip[t*4];
  float wv[9];
  #pragma unroll
  for (int i = 0; i < 9; i++) wv[i] = wdw[c*9+i];
  __syncthreads();
  float o[4]; float ssq = 0.f;
  #pragma unroll
  for (int j = 0; j < 4; j++){
    const int px = t*4 + j, x = px & 31, y = px >> 5;
    float s = 0.f;
    #pragma unroll
    for (int ky = 0; ky < 3; ky++){
      const int yy = y + ky - 1;
      if (yy < 0 || yy > 31) continue;
      #pragma unroll
      for (int kx = 0; kx < 3; kx++){
        const int xx = x + kx - 1;
        if (xx < 0 || xx > 31) continue;
        s = fmaf(tile[yy*32+xx], wv[ky*3+kx], s);
      }
    }
    o[j] = s; ssq += s*s;
  }
  for (int off = 32; off; off >>= 1) ssq += __shfl_down(ssq, off);
  if ((t & 63) == 0) wsum[t >> 6] = ssq;
  __syncthreads();
  float inv = 1.f;
  if (c < 512){
    const float tot = wsum[0]+wsum[1]+wsum[2]+wsum[3];
    inv = 1.f / fmaxf(sqrtf(tot), 1e-12f);
  }
  *(float4*)&out[(size_t)p*1024 + t*4] = make_float4(o[0]*inv, o[1]*inv, o[2]*inv, o[3]*inv);
}

// ---------------- CHA fused: scores + softmax + PV -> chaout bf16 [b][n][256] ----------------
__global__ __launch_bounds__(256) void cha_fused_kernel(const float* __restrict__ qk,
    const float* __restrict__ tempP, ushort* __restrict__ out16){
  __shared__ float qs[32][129], ks[32][129];
  __shared__ float Ss[32][33];
  const int t = threadIdx.x;
  const int bh = blockIdx.x, b = bh >> 3, h = bh & 7;
  const size_t qbase = ((size_t)b*768 + h*32)*1024;
  const size_t kbase = qbase + (size_t)256*1024;
  const int c31 = t & 31, dg = t >> 5;
  float acc[4] = {0.f,0.f,0.f,0.f};
  for (int ch = 0; ch < 8; ch++){
    { const int cs = t >> 3, n0 = (t & 7)*16;
      #pragma unroll
      for (int j = 0; j < 4; j++){
        const float4 vq = *(const float4*)&qk[qbase + (size_t)cs*1024 + ch*128 + n0 + j*4];
        const float4 vk = *(const float4*)&qk[kbase + (size_t)cs*1024 + ch*128 + n0 + j*4];
        qs[cs][n0+j*4+0]=vq.x; qs[cs][n0+j*4+1]=vq.y; qs[cs][n0+j*4+2]=vq.z; qs[cs][n0+j*4+3]=vq.w;
        ks[cs][n0+j*4+0]=vk.x; ks[cs][n0+j*4+1]=vk.y; ks[cs][n0+j*4+2]=vk.z; ks[cs][n0+j*4+3]=vk.w;
      } }
    __syncthreads();
    for (int nn = 0; nn < 128; nn++){
      const float qv = qs[c31][nn];
      #pragma unroll
      for (int j = 0; j < 4; j++) acc[j] = fmaf(qv, ks[dg*4+j][nn], acc[j]);
    }
    __syncthreads();
  }
  const float tf = tempP[h];
  #pragma unroll
  for (int j = 0; j < 4; j++) Ss[c31][dg*4+j] = acc[j]*tf;
  __syncthreads();
  if (t < 32){
    float mx = -1e30f;
    #pragma unroll
    for (int d = 0; d < 32; d++) mx = fmaxf(mx, Ss[t][d]);
    float sum = 0.f; float e[32];
    #pragma unroll
    for (int d = 0; d < 32; d++){ e[d] = __expf(Ss[t][d]-mx); sum += e[d]; }
    const float inv = 1.f/sum;
    #pragma unroll
    for (int d = 0; d < 32; d++) Ss[t][d] = e[d]*inv;
  }
  __syncthreads();
  const int n64 = t & 63, cg = t >> 6;
  const size_t vbase = ((size_t)b*768 + 512 + h*32)*1024;
  for (int ch = 0; ch < 16; ch++){
    const int nb2 = ch*64;
    float acc8[8] = {};
    for (int d = 0; d < 32; d++){
      const float v = qk[vbase + (size_t)d*1024 + nb2 + n64];
      #pragma unroll
      for (int j = 0; j < 8; j++) acc8[j] = fmaf(Ss[cg*8+j][d], v, acc8[j]);
    }
    ushort o8[8];
    #pragma unroll
    for (int j = 0; j < 8; j++) o8[j] = f2bf(acc8[j]);
    *(uint4*)&out16[((size_t)b*NPIX + nb2 + n64)*256 + h*32 + cg*8] = *(uint4*)o8;
  }
}

// ---------------- FFN grouped 3x3 + bias + relu6, LDS-tiled ----------------
__global__ __launch_bounds__(256) void gconv_lds_kernel(const float* __restrict__ in,
    const float* __restrict__ w, const float* __restrict__ bias, float* __restrict__ out){
  __shared__ float tin[2][1024];
  const int p = blockIdx.x;                 // b*512 + o
  const int o = p & 511, b = p >> 9;
  const int t = threadIdx.x;
  const float* ip = in + ((size_t)b*512 + (o & ~1))*1024;
  *(float4*)&tin[0][t*4] = *(const float4*)&ip[t*4];
  *(float4*)&tin[1][t*4] = *(const float4*)&ip[1024 + t*4];
  float wv[18];
  #pragma unroll
  for (int i = 0; i < 18; i++) wv[i] = w[o*18 + i];
  const float bs = bias[o];
  __syncthreads();
  float res[4];
  #pragma unroll
  for (int j = 0; j < 4; j++){
    const int px = t*4 + j, x = px & 31, y = px >> 5;
    float s = bs;
    #pragma unroll
    for (int ci = 0; ci < 2; ci++){
      #pragma unroll
      for (int ky = 0; ky < 3; ky++){
        const int yy = y + ky - 1;
        if (yy < 0 || yy > 31) continue;
        #pragma unroll
        for (int kx = 0; kx < 3; kx++){
          const int xx = x + kx - 1;
          if (xx < 0 || xx > 31) continue;
          s = fmaf(tin[ci][yy*32+xx], wv[ci*9 + ky*3 + kx], s);
        }
      }
    }
    res[j] = fminf(fmaxf(s, 0.f), 6.f);
  }
  *(float4*)&out[(size_t)p*1024 + t*4] = make_float4(res[0], res[1], res[2], res[3]);
}

extern "C" void kernel_launch(void* const* d_in, const int* in_sizes, int n_in,
                              void* d_out, int out_size, void* d_ws, size_t ws_size,
                              hipStream_t stream)
{
  (void)in_sizes; (void)n_in; (void)out_size; (void)ws_size;

  float* ws    = (float*)d_ws;
  float* xbuf  = ws + OFF_XBUF;
  float* parm  = ws + OFF_PARM;
  ushort* Wbf  = (ushort*)(ws + OFF_WBF);
  ushort* QT   = (ushort*)(ws + OFF_QT);
  ushort* V16  = (ushort*)(ws + OFF_V16);
  ushort* att  = (ushort*)(ws + OFF_ATT);
  ushort* cha16= (ushort*)(ws + OFF_ATT);
  float* buf1  = ws + OFF_BUF1;
  float* buf2  = ws + OFF_BUF2;
  float* stats = ws + OFF_STATS;
  float* eff   = ws + OFF_EFF;
  int*  flag   = (int*)(ws + OFF_FLAG);

  detect_kernel<<<1, 256, 0, stream>>>(d_in[0], flag);
  PackArgs pa;
  for (int i = 0; i < 34; i++) pa.p[i] = d_in[i];
  prep_all_kernel<<<1118, 256, 0, stream>>>(pa, flag, parm, Wbf, eff, stats);
  xpose_kernel<<<dim3(16,4,4), 256, 0, stream>>>(d_in[0], flag, xbuf, stats);

  // ---- CDA ----
  gemm_kernel<0,0,false,false,false><<<dim3(16,24,4), 256, 0, stream>>>(
      xbuf, nullptr, Wbf, nullptr, stats, stats+4096, eff, eff+256,
      nullptr, nullptr, nullptr, nullptr, QT, V16, nullptr, 256, nullptr);
  attn_kernel<<<dim3(16,8,4), 256, 0, stream>>>(QT, V16, parm, eff+2560, att);
  gemm_kernel<2,1,false,false,true><<<dim3(16,4,4), 256, 0, stream>>>(
      nullptr, att, Wbf+589824, nullptr, nullptr, nullptr, nullptr, nullptr,
      nullptr, nullptr, xbuf, xbuf, nullptr, nullptr, stats+8192, 512, nullptr);

  // ---- CHA ----
  gemm_kernel<0,2,false,false,false><<<dim3(16,12,4), 256, 0, stream>>>(
      xbuf, nullptr, Wbf+393216, nullptr, stats+8192, stats+12288, eff+512, eff+768,
      nullptr, nullptr, nullptr, buf1, nullptr, nullptr, nullptr, 256, nullptr);
  dwl2_kernel<<<3072, 256, 0, stream>>>(buf1, parm + 72, buf2);
  cha_fused_kernel<<<32, 256, 0, stream>>>(buf2, parm + 64, cha16);
  gemm_kernel<2,1,false,false,true><<<dim3(16,4,4), 256, 0, stream>>>(
      nullptr, cha16, Wbf+720896, nullptr, nullptr, nullptr, nullptr, nullptr,
      nullptr, nullptr, xbuf, xbuf, nullptr, nullptr, stats+16384, 256, nullptr);

  // ---- FFN ----
  gemm_kernel<0,2,true,true,false><<<dim3(16,8,4), 256, 0, stream>>>(
      xbuf, nullptr, Wbf+786432, parm+6984, stats+16384, stats+20480, eff+1024, eff+1280,
      eff+1536, eff+2048, nullptr, buf1, nullptr, nullptr, nullptr, 256, nullptr);
  gconv_lds_kernel<<<2048, 256, 0, stream>>>(buf1, parm+7496, parm+16712, buf2);
  gemm_kernel<1,3,true,false,false><<<dim3(16,4,4), 256, 0, stream>>>(
      buf2, nullptr, Wbf+917504, parm+17224, nullptr, nullptr, nullptr, nullptr,
      nullptr, nullptr, xbuf, d_out, nullptr, nullptr, nullptr, 512, flag);
}

// Round 10
// 294.178 us; speedup vs baseline: 1.3669x; 1.3669x over previous
//
#include <hip/hip_runtime.h>
#include <hip/hip_bf16.h>

typedef __hip_bfloat16 bf16;
typedef __attribute__((ext_vector_type(8))) short s16x8;
typedef __attribute__((ext_vector_type(4))) float f32x4;

#define DEV __device__ __forceinline__

DEV float b2f(bf16 v){ return __bfloat162float(v); }
DEV ushort f2bf(float f){ bf16 h = __float2bfloat16(f); return *reinterpret_cast<ushort*>(&h); }
DEV float bf2f(ushort u){ bf16 h; *reinterpret_cast<ushort*>(&h) = u; return __bfloat162float(h); }

constexpr int NPIX = 1024;
constexpr float EPSF = 1e-5f;
constexpr float LAMBDA_INIT_F = 0.3555090675909693f;
constexpr float ONE_M_LI     = 0.6444909324090307f;
constexpr float ATT_SCALE    = 0.17677669529663687f;

// workspace offsets (floats)
constexpr size_t OFF_XBUF  = 0;         // f32 [4][1024][256] residual, channel-last
constexpr size_t OFF_PARM  = 1048576;   // 17480 small params
constexpr size_t OFF_WBF   = 2120448;   // bf16 weights (1048576 ushorts)
constexpr size_t OFF_QT    = 2644736;   // QT/KT bf16 [2][4][8][1024][64]
constexpr size_t OFF_V16   = 4741888;   // V bf16 [4][512][1024]
constexpr size_t OFF_ATT   = 5790464;   // att bf16 [4][1024][512]; later chaout bf16 [4][1024][256]
constexpr size_t OFF_BUF1  = 6839040;   // f32 [4][768][1024] qkv / ffn1 (channel-first)
constexpr size_t OFF_BUF2  = 9984768;   // f32 dw / gconv out (channel-first)
constexpr size_t OFF_SPART = 13130496;  // 262144 cha partial scores
constexpr size_t OFF_STATS = 13425408;  // 3 x [sum 4096 | sq 4096]
constexpr size_t OFF_EFF   = 13449984;  // folded params (2560) + lam(8)
constexpr size_t OFF_FLAG  = 13452608;

struct PackArgs { const void* p[34]; };

// ---------------- dtype detect ----------------
__global__ __launch_bounds__(256) void detect_kernel(const void* __restrict__ x, int* __restrict__ flag){
  __shared__ int sh;
  if (threadIdx.x == 0) sh = 0;
  __syncthreads();
  const bf16* h = (const bf16*)x;
  int local = 0;
  for (int i = threadIdx.x; i < 4096; i += 256){
    float v = b2f(h[i]);
    if (!(fabsf(v) <= 1e6f)) local = 1;
  }
  if (local) atomicOr(&sh, 1);
  __syncthreads();
  if (threadIdx.x == 0) *flag = sh;
}

DEV float rdin(const PackArgs& a, int i, int idx, int flag){
  return flag ? ((const float*)a.p[i])[idx] : b2f(((const bf16*)a.p[i])[idx]);
}

// ---------------- prep: parm pack + Wbf pack + eff/lam + zero stats ----------------
__global__ __launch_bounds__(256) void prep_all_kernel(PackArgs args, const int* __restrict__ flagp,
    float* __restrict__ parm, ushort* __restrict__ W, float* __restrict__ eff, float* __restrict__ stats){
  const int t = threadIdx.x;
  const int blk = blockIdx.x;
  const int flag = *flagp;
  if (blk < 69){
    const int g = blk*256 + t;
    if (g >= 17480) return;
    int src, loc;
    if      (g < 64)    { src = 10; loc = g; }
    else if (g < 72)    { src = 14; loc = g - 64; }
    else if (g < 6984)  { src = 16; loc = g - 72; }
    else if (g < 7496)  { src = 25; loc = g - 6984; }
    else if (g < 16712) { src = 30; loc = g - 7496; }
    else if (g < 17224) { src = 31; loc = g - 16712; }
    else                { src = 33; loc = g - 17224; }
    parm[g] = rdin(args, src, loc, flag);
  } else if (blk < 1093){
    const int g = (blk - 69)*1024 + t*4;     // < 1048576
    int src, loc;
    if      (g <  131072){ src = 3;  loc = g; }
    else if (g <  262144){ src = 4;  loc = g - 131072; }
    else if (g <  393216){ src = 5;  loc = g - 262144; }
    else if (g <  589824){ src = 15; loc = g - 393216; }
    else if (g <  720896){ src = 11; loc = g - 589824; }
    else if (g <  786432){ src = 17; loc = g - 720896; }
    else if (g <  917504){ src = 24; loc = g - 786432; }
    else                 { src = 32; loc = g - 917504; }
    ushort4 o;
    if (flag){
      const float4 v = *(const float4*)((const float*)args.p[src] + loc);
      o = make_ushort4(f2bf(v.x), f2bf(v.y), f2bf(v.z), f2bf(v.w));
    } else {
      o = *(const ushort4*)((const ushort*)args.p[src] + loc);
    }
    *(ushort4*)&W[g] = o;
  } else if (blk == 1093){
    eff[t]      = rdin(args,1,t,flag);  eff[256+t] = rdin(args,2,t,flag);
    eff[512+t]  = rdin(args,12,t,flag); eff[768+t] = rdin(args,13,t,flag);
    const float s1 = rdin(args,20,t,flag) * rsqrtf(rdin(args,23,t,flag) + EPSF);
    eff[1024+t] = rdin(args,18,t,flag) * s1;
    eff[1280+t] = (rdin(args,19,t,flag) - rdin(args,22,t,flag)) * s1 + rdin(args,21,t,flag);
    for (int c = t; c < 512; c += 256){
      const float sc = rdin(args,26,c,flag) * rsqrtf(rdin(args,29,c,flag) + EPSF);
      eff[1536+c] = sc;
      eff[2048+c] = rdin(args,27,c,flag) - rdin(args,28,c,flag)*sc;
    }
    if (t < 8){
      float e1 = 0.f, e2 = 0.f;
      for (int i = 0; i < 32; i++){
        e1 += rdin(args,6,t*32+i,flag) * rdin(args,7,t*32+i,flag);
        e2 += rdin(args,8,t*32+i,flag) * rdin(args,9,t*32+i,flag);
      }
      eff[2560+t] = __expf(e1) - __expf(e2) + LAMBDA_INIT_F;
    }
  } else {
    // 1094..1117: zero all 3 stats sections (24576 floats)
    const int i = (blk - 1094)*1024 + t*4;
    *(float4*)&stats[i] = make_float4(0.f,0.f,0.f,0.f);
  }
}

// ---------------- xpose: x [b][c][n] -> xbuf [b][n][c] f32 + LN1 raw stats ----------------
__global__ __launch_bounds__(256) void xpose_kernel(const void* __restrict__ xin,
    const int* __restrict__ flagp, float* __restrict__ xb, float* __restrict__ stats){
  __shared__ float T[64][68];
  __shared__ float psum[64][4], psq[64][4];
  const int t = threadIdx.x;
  const int nt = blockIdx.x*64, ct = blockIdx.y*64, b = blockIdx.z;
  const int flag = *flagp;
  { const int c_ = t >> 2, nq = t & 3;
    const size_t base = ((size_t)b*256 + ct + c_)*1024 + nt + nq*16;
    float tmp[16];
    if (flag){
      #pragma unroll
      for (int j = 0; j < 4; j++){
        const float4 v = *(const float4*)((const float*)xin + base + j*4);
        tmp[j*4+0]=v.x; tmp[j*4+1]=v.y; tmp[j*4+2]=v.z; tmp[j*4+3]=v.w;
      }
    } else {
      const ushort* xh = (const ushort*)xin + base;
      #pragma unroll
      for (int j = 0; j < 2; j++){
        uint4 u = *(const uint4*)(xh + j*8);
        const ushort* us = (const ushort*)&u;
        #pragma unroll
        for (int k = 0; k < 8; k++) tmp[j*8+k] = bf2f(us[k]);
      }
    }
    #pragma unroll
    for (int j = 0; j < 4; j++)
      *(float4*)&T[c_][nq*16 + j*4] = make_float4(tmp[j*4],tmp[j*4+1],tmp[j*4+2],tmp[j*4+3]);
  }
  __syncthreads();
  { const int n_ = t >> 2, cq = t & 3;
    float s = 0.f, q = 0.f;
    float tmp[16];
    #pragma unroll
    for (int i = 0; i < 16; i++){
      const float v = T[cq*16 + i][n_];
      tmp[i] = v; s += v; q += v*v;
    }
    #pragma unroll
    for (int j = 0; j < 4; j++)
      *(float4*)&xb[((size_t)b*NPIX + nt + n_)*256 + ct + cq*16 + j*4] =
          make_float4(tmp[j*4],tmp[j*4+1],tmp[j*4+2],tmp[j*4+3]);
    psum[n_][cq] = s; psq[n_][cq] = q;
  }
  __syncthreads();
  if (t < 64){
    const float s = psum[t][0]+psum[t][1]+psum[t][2]+psum[t][3];
    const float q = psq[t][0]+psq[t][1]+psq[t][2]+psq[t][3];
    atomicAdd(&stats[(size_t)b*NPIX + nt + t], s);
    atomicAdd(&stats[4096 + (size_t)b*NPIX + nt + t], q);
  }
}

// ---------------- unified MFMA GEMM ----------------
// IN: 0 = f32 [b][n][Cin] + LN(raw stats); 1 = f32 [b][c][n] plain; 2 = bf16 [b][n][Cin]
// EPI: 0 = QKV special; 1 = f32 [n][c] +res (opt STATS); 2 = f32 [c][n] (+bias)(+bn2); 3 = final d_out
template<int INM, int EPIM, bool BIAS, bool BN2F, bool STATS>
__global__ __launch_bounds__(256) void gemm_kernel(
    const float* __restrict__ Xf, const ushort* __restrict__ Xb, const ushort* __restrict__ W,
    const float* __restrict__ bias, const float* __restrict__ mu, const float* __restrict__ rstd,
    const float* __restrict__ effw, const float* __restrict__ effb,
    const float* __restrict__ s2, const float* __restrict__ t2,
    const float* __restrict__ res, void* __restrict__ out,
    ushort* __restrict__ qt, ushort* __restrict__ v16,
    float* __restrict__ gstats,
    int Cin, const int* __restrict__ flag)
{
  __shared__ ushort Xt[64][72];
  const int t = threadIdx.x;
  const int nb = blockIdx.x*64, ob = blockIdx.y*64, b = blockIdx.z;
  const int lane = t & 63, w = t >> 6;
  const int wR = w >> 1, wC = w & 1;
  const int l15 = lane & 15, g = lane >> 4;
  const int tn = t & 63, tc4 = t >> 6;
  const f32x4 z4 = {0.f,0.f,0.f,0.f};
  f32x4 acc[2][2] = {{z4,z4},{z4,z4}};

  float m_ = 0.f, r_ = 1.f;
  if (INM == 0){
    const int n_ = t >> 2;
    const float sv = mu[(size_t)b*NPIX + nb + n_];
    const float qv = rstd[(size_t)b*NPIX + nb + n_];
    m_ = sv * (1.f/256.f);
    r_ = rsqrtf(fmaxf(qv*(1.f/256.f) - m_*m_, 0.f) + EPSF);
  }

  for (int kb = 0; kb < Cin; kb += 64){
    if (INM == 2){
      const ushort* src = Xb + ((size_t)b*NPIX + nb + tn)*Cin + kb + tc4*16;
      *(uint4*)&Xt[tn][tc4*16]   = *(const uint4*)src;
      *(uint4*)&Xt[tn][tc4*16+8] = *(const uint4*)(src+8);
    } else if (INM == 0){
      const int n_ = t >> 2, cq = t & 3;
      const float* src = Xf + ((size_t)b*NPIX + nb + n_)*Cin + kb + cq*16;
      float f[16];
      #pragma unroll
      for (int j = 0; j < 4; j++){
        const float4 v = *(const float4*)(src + j*4);
        f[j*4+0]=v.x; f[j*4+1]=v.y; f[j*4+2]=v.z; f[j*4+3]=v.w;
      }
      ushort tmp[16];
      #pragma unroll
      for (int i = 0; i < 16; i++){
        const int c = kb + cq*16 + i;
        tmp[i] = f2bf((f[i] - m_)*r_*effw[c] + effb[c]);
      }
      *(uint4*)&Xt[n_][cq*16]   = *(uint4*)&tmp[0];
      *(uint4*)&Xt[n_][cq*16+8] = *(uint4*)&tmp[8];
    } else {
      ushort tmp[16];
      #pragma unroll
      for (int i = 0; i < 16; i++){
        const int c = kb + tc4*16 + i;
        tmp[i] = f2bf(Xf[((size_t)b*Cin + c)*NPIX + nb + tn]);
      }
      *(uint4*)&Xt[tn][tc4*16]   = *(uint4*)&tmp[0];
      *(uint4*)&Xt[tn][tc4*16+8] = *(uint4*)&tmp[8];
    }
    __syncthreads();
    #pragma unroll
    for (int ks = 0; ks < 2; ks++){
      const s16x8 a0 = *(const s16x8*)&W[(size_t)(ob + wR*32 + l15)*Cin + kb + ks*32 + g*8];
      const s16x8 a1 = *(const s16x8*)&W[(size_t)(ob + wR*32 + 16 + l15)*Cin + kb + ks*32 + g*8];
      const s16x8 b0 = *(const s16x8*)&Xt[wC*32 + l15][ks*32 + g*8];
      const s16x8 b1 = *(const s16x8*)&Xt[wC*32 + 16 + l15][ks*32 + g*8];
      acc[0][0] = __builtin_amdgcn_mfma_f32_16x16x32_bf16(a0, b0, acc[0][0], 0,0,0);
      acc[0][1] = __builtin_amdgcn_mfma_f32_16x16x32_bf16(a0, b1, acc[0][1], 0,0,0);
      acc[1][0] = __builtin_amdgcn_mfma_f32_16x16x32_bf16(a1, b0, acc[1][0], 0,0,0);
      acc[1][1] = __builtin_amdgcn_mfma_f32_16x16x32_bf16(a1, b1, acc[1][1], 0,0,0);
    }
    __syncthreads();
  }

  const int Cout = gridDim.y*64;
  const int fl = (EPIM == 3) ? *flag : 0;
  float sst[2] = {0.f, 0.f}, qst[2] = {0.f, 0.f};
  #pragma unroll
  for (int fr = 0; fr < 2; fr++){
    #pragma unroll
    for (int fc = 0; fc < 2; fc++){
      const int o = ob + wR*32 + fr*16 + 4*g;
      const int n = nb + wC*32 + fc*16 + l15;
      const f32x4 v = acc[fr][fc];
      if (EPIM == 0){
        if (ob < 1024){
          const int qk = o >> 9, h = (o >> 6) & 7, d = o & 63;
          ushort4 pk = make_ushort4(f2bf(v[0]), f2bf(v[1]), f2bf(v[2]), f2bf(v[3]));
          ushort* dst = qt + ((((size_t)qk*4 + b)*8 + h)*NPIX + n)*64 + d;
          *(ushort4*)dst = pk;
        } else {
          const int c = o - 1024;
          #pragma unroll
          for (int r = 0; r < 4; r++)
            v16[((size_t)b*512 + c + r)*NPIX + n] = f2bf(v[r]);
        }
      } else if (EPIM == 1){
        const size_t row = ((size_t)b*NPIX + n)*Cout + o;
        const float4 r4 = *(const float4*)&res[row];
        float vals[4];
        #pragma unroll
        for (int r = 0; r < 4; r++){
          float val = v[r];
          if (BIAS) val += bias[o+r];
          if (BN2F) val = val*s2[o+r] + t2[o+r];
          vals[r] = val + ((const float*)&r4)[r];
        }
        *(float4*)&((float*)out)[row] = make_float4(vals[0],vals[1],vals[2],vals[3]);
        if (STATS){
          sst[fc] += vals[0]+vals[1]+vals[2]+vals[3];
          qst[fc] += vals[0]*vals[0]+vals[1]*vals[1]+vals[2]*vals[2]+vals[3]*vals[3];
        }
      } else if (EPIM == 2){
        #pragma unroll
        for (int r = 0; r < 4; r++){
          float val = v[r];
          if (BIAS) val += bias[o + r];
          if (BN2F) val = val*s2[o+r] + t2[o+r];
          ((float*)out)[((size_t)b*Cout + o + r)*NPIX + n] = val;
        }
      } else {
        const float4 r4 = *(const float4*)&res[((size_t)b*NPIX + n)*256 + o];
        #pragma unroll
        for (int r = 0; r < 4; r++){
          float val = v[r] + ((const float*)&r4)[r];
          if (BIAS) val += bias[o+r];
          const size_t row = ((size_t)b*256 + o + r)*NPIX + n;
          if (fl) ((float*)out)[row] = val;
          else    ((ushort*)out)[row] = f2bf(val);
        }
      }
    }
  }
  if (STATS){
    float* sacc = (float*)&Xt[0][0];
    if (t < 128) sacc[t] = 0.f;
    __syncthreads();
    #pragma unroll
    for (int fc = 0; fc < 2; fc++){
      const int nl = wC*32 + fc*16 + l15;
      atomicAdd(&sacc[nl*2+0], sst[fc]);
      atomicAdd(&sacc[nl*2+1], qst[fc]);
    }
    __syncthreads();
    if (t < 64){
      atomicAdd(&gstats[(size_t)b*NPIX + nb + t],        sacc[t*2+0]);
      atomicAdd(&gstats[4096 + (size_t)b*NPIX + nb + t], sacc[t*2+1]);
    }
  }
}

// ---------------- MFMA differential attention, LDS-staged K/V ----------------
__global__ __launch_bounds__(256) void attn_kernel(
    const ushort* __restrict__ QT, const ushort* __restrict__ V16,
    const float* __restrict__ rms, const float* __restrict__ lamArr,
    ushort* __restrict__ att)
{
  __shared__ ushort Ks[2][4096];
  __shared__ ushort Vs[2][4096];
  const int t = threadIdx.x;
  const int lane = t & 63, w = t >> 6;
  const int l15 = lane & 15, g = lane >> 4;
  const int qt = blockIdx.x, h = blockIdx.y, b = blockIdx.z;
  const int qsub = qt*64 + w*16;
  const ushort* Qb = QT + ((size_t)b*8 + h)*NPIX*64;
  const ushort* Kb = QT + ((size_t)(4 + b)*8 + h)*NPIX*64;
  const ushort* Vb = V16 + ((size_t)b*512 + h*64)*NPIX;

  const int c0row = t >> 3, c0col = t & 7;
  const int c1row = (t + 256) >> 3, c1col = t & 7;
  const int sw0 = (c0col ^ (c0row & 7))*8;
  const int sw1 = (c1col ^ (c1row & 7))*8;

  s16x8 bq[2];
  #pragma unroll
  for (int hx = 0; hx < 2; hx++)
    bq[hx] = *(const s16x8*)&Qb[(size_t)(qsub + l15)*64 + 32*hx + 8*g];
  const float lam = lamArr[h];

  const f32x4 z4 = {0.f,0.f,0.f,0.f};
  f32x4 o0[4] = {z4,z4,z4,z4};
  f32x4 o1[4] = {z4,z4,z4,z4};
  float z[2] = {0.f, 0.f};

  uint4 kra = *(const uint4*)&Kb[(size_t)c0row*64 + c0col*8];
  uint4 krb = *(const uint4*)&Kb[(size_t)c1row*64 + c1col*8];
  uint4 vra = *(const uint4*)&Vb[(size_t)c0row*NPIX + c0col*8];
  uint4 vrb = *(const uint4*)&Vb[(size_t)c1row*NPIX + c1col*8];
  *(uint4*)&Ks[0][c0row*64 + sw0] = kra;
  *(uint4*)&Ks[0][c1row*64 + sw1] = krb;
  *(uint4*)&Vs[0][c0row*64 + sw0] = vra;
  *(uint4*)&Vs[0][c1row*64 + sw1] = vrb;
  kra = *(const uint4*)&Kb[(size_t)(64 + c0row)*64 + c0col*8];
  krb = *(const uint4*)&Kb[(size_t)(64 + c1row)*64 + c1col*8];
  vra = *(const uint4*)&Vb[(size_t)c0row*NPIX + 64 + c0col*8];
  vrb = *(const uint4*)&Vb[(size_t)c1row*NPIX + 64 + c1col*8];
  __syncthreads();

  #pragma unroll 1
  for (int it = 0; it < 16; it++){
    const int cur = it & 1;
    const ushort* Kc = &Ks[cur][0];
    const ushort* Vc = &Vs[cur][0];

    f32x4 s[2][4];
    #pragma unroll
    for (int fr = 0; fr < 4; fr++){
      const int row = fr*16 + l15;
      const int rx = (row & 7)*8;
      #pragma unroll
      for (int hx = 0; hx < 2; hx++){
        const s16x8 ak = *(const s16x8*)&Kc[row*64 + ((hx*32 + 8*g) ^ rx)];
        s[hx][fr] = __builtin_amdgcn_mfma_f32_16x16x32_bf16(ak, bq[hx], z4, 0,0,0);
      }
    }
    s16x8 pa[2][2];
    #pragma unroll
    for (int hx = 0; hx < 2; hx++){
      #pragma unroll
      for (int ms = 0; ms < 2; ms++){
        ushort tmp[8];
        #pragma unroll
        for (int fr2 = 0; fr2 < 2; fr2++)
          #pragma unroll
          for (int r = 0; r < 4; r++){
            const float e = __expf(s[hx][ms*2 + fr2][r] * ATT_SCALE);
            z[hx] += e;
            tmp[fr2*4 + r] = f2bf(e);
          }
        pa[hx][ms] = *(s16x8*)tmp;
      }
    }
    __builtin_amdgcn_s_setprio(1);
    #pragma unroll
    for (int ms = 0; ms < 2; ms++){
      #pragma unroll
      for (int dc = 0; dc < 4; dc++){
        const int row = dc*16 + l15;
        const int r7 = row & 7;
        const int elo = ms*32 + 4*g;
        const int eloswz = ((((elo >> 3) ^ r7) << 3) | (elo & 7));
        const int ehi = elo + 16;
        const int ehiswz = ((((ehi >> 3) ^ r7) << 3) | (ehi & 7));
        const uint2 lo = *(const uint2*)&Vc[row*64 + eloswz];
        const uint2 hi = *(const uint2*)&Vc[row*64 + ehiswz];
        union { uint u[4]; s16x8 v; } bv;
        bv.u[0] = lo.x; bv.u[1] = lo.y; bv.u[2] = hi.x; bv.u[3] = hi.y;
        o0[dc] = __builtin_amdgcn_mfma_f32_16x16x32_bf16(pa[0][ms], bv.v, o0[dc], 0,0,0);
        o1[dc] = __builtin_amdgcn_mfma_f32_16x16x32_bf16(pa[1][ms], bv.v, o1[dc], 0,0,0);
      }
    }
    __builtin_amdgcn_s_setprio(0);

    if (it < 15){
      const int nxt = cur ^ 1;
      *(uint4*)&Ks[nxt][c0row*64 + sw0] = kra;
      *(uint4*)&Ks[nxt][c1row*64 + sw1] = krb;
      *(uint4*)&Vs[nxt][c0row*64 + sw0] = vra;
      *(uint4*)&Vs[nxt][c1row*64 + sw1] = vrb;
      if (it < 14){
        const int m0 = (it + 2)*64;
        kra = *(const uint4*)&Kb[(size_t)(m0 + c0row)*64 + c0col*8];
        krb = *(const uint4*)&Kb[(size_t)(m0 + c1row)*64 + c1col*8];
        vra = *(const uint4*)&Vb[(size_t)c0row*NPIX + m0 + c0col*8];
        vrb = *(const uint4*)&Vb[(size_t)c1row*NPIX + m0 + c1col*8];
      }
    }
    __syncthreads();
  }

  #pragma unroll
  for (int hx = 0; hx < 2; hx++){
    z[hx] += __shfl_xor(z[hx], 16);
    z[hx] += __shfl_xor(z[hx], 32);
  }
  float zi0[4], zi1[4];
  #pragma unroll
  for (int r = 0; r < 4; r++){
    zi0[r] = 1.f / __shfl(z[0], 4*g + r);
    zi1[r] = 1.f / __shfl(z[1], 4*g + r);
  }
  float val[4][4];
  float ss[4] = {0.f,0.f,0.f,0.f};
  #pragma unroll
  for (int dc = 0; dc < 4; dc++)
    #pragma unroll
    for (int r = 0; r < 4; r++){
      const float vv = o0[dc][r]*zi0[r] - lam*o1[dc][r]*zi1[r];
      val[dc][r] = vv; ss[r] += vv*vv;
    }
  #pragma unroll
  for (int r = 0; r < 4; r++){
    ss[r] += __shfl_xor(ss[r], 1);
    ss[r] += __shfl_xor(ss[r], 2);
    ss[r] += __shfl_xor(ss[r], 4);
    ss[r] += __shfl_xor(ss[r], 8);
  }
  float rinv[4];
  #pragma unroll
  for (int r = 0; r < 4; r++) rinv[r] = ONE_M_LI * rsqrtf(ss[r]*(1.f/64.f) + EPSF);
  #pragma unroll
  for (int dc = 0; dc < 4; dc++){
    const float rs = rms[dc*16 + l15];
    #pragma unroll
    for (int r = 0; r < 4; r++){
      const int n = qsub + 4*g + r;
      att[((size_t)b*NPIX + n)*512 + h*64 + dc*16 + l15] = f2bf(val[dc][r]*rinv[r]*rs);
    }
  }
}

// ---------------- fused depthwise 3x3 + L2-norm (block = plane) ----------------
__global__ __launch_bounds__(256) void dwl2_kernel(const float* __restrict__ in,
    const float* __restrict__ wdw, float* __restrict__ out){
  __shared__ float tile[1024];
  __shared__ float wsum[4];
  const int p = blockIdx.x;                 // b*768 + c
  const int c = p % 768;
  const int t = threadIdx.x;
  const float* ip = in + (size_t)p*1024;
  *(float4*)&tile[t*4] = *(const float4*)&ip[t*4];
  float wv[9];
  #pragma unroll
  for (int i = 0; i < 9; i++) wv[i] = wdw[c*9+i];
  __syncthreads();
  float o[4]; float ssq = 0.f;
  #pragma unroll
  for (int j = 0; j < 4; j++){
    const int px = t*4 + j, x = px & 31, y = px >> 5;
    float s = 0.f;
    #pragma unroll
    for (int ky = 0; ky < 3; ky++){
      const int yy = y + ky - 1;
      if (yy < 0 || yy > 31) continue;
      #pragma unroll
      for (int kx = 0; kx < 3; kx++){
        const int xx = x + kx - 1;
        if (xx < 0 || xx > 31) continue;
        s = fmaf(tile[yy*32+xx], wv[ky*3+kx], s);
      }
    }
    o[j] = s; ssq += s*s;
  }
  for (int off = 32; off; off >>= 1) ssq += __shfl_down(ssq, off);
  if ((t & 63) == 0) wsum[t >> 6] = ssq;
  __syncthreads();
  float inv = 1.f;
  if (c < 512){
    const float tot = wsum[0]+wsum[1]+wsum[2]+wsum[3];
    inv = 1.f / fmaxf(sqrtf(tot), 1e-12f);
  }
  *(float4*)&out[(size_t)p*1024 + t*4] = make_float4(o[0]*inv, o[1]*inv, o[2]*inv, o[3]*inv);
}

// ---------------- CHA partial scores ----------------
__global__ __launch_bounds__(256) void cha_scores_kernel(const float* __restrict__ qk,
                                                         float* __restrict__ spart){
  __shared__ float qs[32][129];
  __shared__ float ks[32][129];
  const int t = threadIdx.x;
  const int nb = blockIdx.x*128;
  const int bh = blockIdx.y, b = bh >> 3, h = bh & 7;
  const size_t qbase = ((size_t)b*768 + h*32)*NPIX + nb;
  const size_t kbase = qbase + (size_t)256*NPIX;
  { const int c = t >> 3, n0 = (t & 7)*16;
    #pragma unroll
    for (int j = 0; j < 4; j++){
      const float4 vq = *(const float4*)&qk[qbase + (size_t)c*NPIX + n0 + j*4];
      const float4 vk = *(const float4*)&qk[kbase + (size_t)c*NPIX + n0 + j*4];
      qs[c][n0+j*4+0]=vq.x; qs[c][n0+j*4+1]=vq.y; qs[c][n0+j*4+2]=vq.z; qs[c][n0+j*4+3]=vq.w;
      ks[c][n0+j*4+0]=vk.x; ks[c][n0+j*4+1]=vk.y; ks[c][n0+j*4+2]=vk.z; ks[c][n0+j*4+3]=vk.w;
    } }
  __syncthreads();
  const int c = t & 31, dg = t >> 5;
  float acc[4] = {};
  for (int nn = 0; nn < 128; nn++){
    const float qv = qs[c][nn];
    #pragma unroll
    for (int j = 0; j < 4; j++) acc[j] = fmaf(qv, ks[dg*4+j][nn], acc[j]);
  }
  float* sp = spart + ((size_t)bh*8 + blockIdx.x)*1024 + c*32 + dg*4;
  #pragma unroll
  for (int j = 0; j < 4; j++) sp[j] = acc[j];
}

// ---------------- CHA softmax + PV -> chaout bf16 [b][n][256] ----------------
__global__ __launch_bounds__(256) void cha_pv_kernel(const float* __restrict__ spart,
    const float* __restrict__ tempP, const float* __restrict__ qkv, ushort* __restrict__ out16){
  __shared__ float Ps[32][33];
  const int t = threadIdx.x;
  const int bh = blockIdx.y, b = bh >> 3, h = bh & 7;
  const int nb = blockIdx.x*64;
  const float tf = tempP[h];
  for (int p = t; p < 1024; p += 256){
    float s = 0.f;
    #pragma unroll
    for (int ch = 0; ch < 8; ch++) s += spart[((size_t)bh*8 + ch)*1024 + p];
    Ps[p >> 5][p & 31] = s * tf;
  }
  __syncthreads();
  if (t < 32){
    float mx = -1e30f;
    #pragma unroll
    for (int d = 0; d < 32; d++) mx = fmaxf(mx, Ps[t][d]);
    float sum = 0.f; float e[32];
    #pragma unroll
    for (int d = 0; d < 32; d++){ e[d] = __expf(Ps[t][d]-mx); sum += e[d]; }
    const float inv = 1.f/sum;
    #pragma unroll
    for (int d = 0; d < 32; d++) Ps[t][d] = e[d]*inv;
  }
  __syncthreads();
  const int n = nb + (t & 63);
  const int cg = t >> 6;
  const size_t vbase = ((size_t)b*768 + 512 + h*32)*NPIX + n;
  float acc[8] = {};
  for (int d = 0; d < 32; d++){
    const float v = qkv[vbase + (size_t)d*NPIX];
    #pragma unroll
    for (int j = 0; j < 8; j++) acc[j] = fmaf(Ps[cg*8+j][d], v, acc[j]);
  }
  ushort o8[8];
  #pragma unroll
  for (int j = 0; j < 8; j++) o8[j] = f2bf(acc[j]);
  *(uint4*)&out16[((size_t)b*NPIX + n)*256 + h*32 + cg*8] = *(uint4*)o8;
}

// ---------------- FFN grouped 3x3 + bias + relu6, LDS-tiled ----------------
__global__ __launch_bounds__(256) void gconv_lds_kernel(const float* __restrict__ in,
    const float* __restrict__ w, const float* __restrict__ bias, float* __restrict__ out){
  __shared__ float tin[2][1024];
  const int p = blockIdx.x;                 // b*512 + o
  const int o = p & 511, b = p >> 9;
  const int t = threadIdx.x;
  const float* ip = in + ((size_t)b*512 + (o & ~1))*1024;
  *(float4*)&tin[0][t*4] = *(const float4*)&ip[t*4];
  *(float4*)&tin[1][t*4] = *(const float4*)&ip[1024 + t*4];
  float wv[18];
  #pragma unroll
  for (int i = 0; i < 18; i++) wv[i] = w[o*18 + i];
  const float bs = bias[o];
  __syncthreads();
  float res[4];
  #pragma unroll
  for (int j = 0; j < 4; j++){
    const int px = t*4 + j, x = px & 31, y = px >> 5;
    float s = bs;
    #pragma unroll
    for (int ci = 0; ci < 2; ci++){
      #pragma unroll
      for (int ky = 0; ky < 3; ky++){
        const int yy = y + ky - 1;
        if (yy < 0 || yy > 31) continue;
        #pragma unroll
        for (int kx = 0; kx < 3; kx++){
          const int xx = x + kx - 1;
          if (xx < 0 || xx > 31) continue;
          s = fmaf(tin[ci][yy*32+xx], wv[ci*9 + ky*3 + kx], s);
        }
      }
    }
    res[j] = fminf(fmaxf(s, 0.f), 6.f);
  }
  *(float4*)&out[(size_t)p*1024 + t*4] = make_float4(res[0], res[1], res[2], res[3]);
}

extern "C" void kernel_launch(void* const* d_in, const int* in_sizes, int n_in,
                              void* d_out, int out_size, void* d_ws, size_t ws_size,
                              hipStream_t stream)
{
  (void)in_sizes; (void)n_in; (void)out_size; (void)ws_size;

  float* ws    = (float*)d_ws;
  float* xbuf  = ws + OFF_XBUF;
  float* parm  = ws + OFF_PARM;
  ushort* Wbf  = (ushort*)(ws + OFF_WBF);
  ushort* QT   = (ushort*)(ws + OFF_QT);
  ushort* V16  = (ushort*)(ws + OFF_V16);
  ushort* att  = (ushort*)(ws + OFF_ATT);
  ushort* cha16= (ushort*)(ws + OFF_ATT);
  float* buf1  = ws + OFF_BUF1;
  float* buf2  = ws + OFF_BUF2;
  float* spart = ws + OFF_SPART;
  float* stats = ws + OFF_STATS;
  float* eff   = ws + OFF_EFF;
  int*  flag   = (int*)(ws + OFF_FLAG);

  detect_kernel<<<1, 256, 0, stream>>>(d_in[0], flag);
  PackArgs pa;
  for (int i = 0; i < 34; i++) pa.p[i] = d_in[i];
  prep_all_kernel<<<1118, 256, 0, stream>>>(pa, flag, parm, Wbf, eff, stats);
  xpose_kernel<<<dim3(16,4,4), 256, 0, stream>>>(d_in[0], flag, xbuf, stats);

  // ---- CDA ----
  gemm_kernel<0,0,false,false,false><<<dim3(16,24,4), 256, 0, stream>>>(
      xbuf, nullptr, Wbf, nullptr, stats, stats+4096, eff, eff+256,
      nullptr, nullptr, nullptr, nullptr, QT, V16, nullptr, 256, nullptr);
  attn_kernel<<<dim3(16,8,4), 256, 0, stream>>>(QT, V16, parm, eff+2560, att);
  gemm_kernel<2,1,false,false,true><<<dim3(16,4,4), 256, 0, stream>>>(
      nullptr, att, Wbf+589824, nullptr, nullptr, nullptr, nullptr, nullptr,
      nullptr, nullptr, xbuf, xbuf, nullptr, nullptr, stats+8192, 512, nullptr);

  // ---- CHA ----
  gemm_kernel<0,2,false,false,false><<<dim3(16,12,4), 256, 0, stream>>>(
      xbuf, nullptr, Wbf+393216, nullptr, stats+8192, stats+12288, eff+512, eff+768,
      nullptr, nullptr, nullptr, buf1, nullptr, nullptr, nullptr, 256, nullptr);
  dwl2_kernel<<<3072, 256, 0, stream>>>(buf1, parm + 72, buf2);
  cha_scores_kernel<<<dim3(8,32), 256, 0, stream>>>(buf2, spart);
  cha_pv_kernel<<<dim3(16,32), 256, 0, stream>>>(spart, parm + 64, buf2, cha16);
  gemm_kernel<2,1,false,false,true><<<dim3(16,4,4), 256, 0, stream>>>(
      nullptr, cha16, Wbf+720896, nullptr, nullptr, nullptr, nullptr, nullptr,
      nullptr, nullptr, xbuf, xbuf, nullptr, nullptr, stats+16384, 256, nullptr);

  // ---- FFN ----
  gemm_kernel<0,2,true,true,false><<<dim3(16,8,4), 256, 0, stream>>>(
      xbuf, nullptr, Wbf+786432, parm+6984, stats+16384, stats+20480, eff+1024, eff+1280,
      eff+1536, eff+2048, nullptr, buf1, nullptr, nullptr, nullptr, 256, nullptr);
  gconv_lds_kernel<<<2048, 256, 0, stream>>>(buf1, parm+7496, parm+16712, buf2);
  gemm_kernel<1,3,true,false,false><<<dim3(16,4,4), 256, 0, stream>>>(
      buf2, nullptr, Wbf+917504, parm+17224, nullptr, nullptr, nullptr, nullptr,
      nullptr, nullptr, xbuf, d_out, nullptr, nullptr, nullptr, 512, flag);
}

// Round 11
// 293.149 us; speedup vs baseline: 1.3717x; 1.0035x over previous
//
#include <hip/hip_runtime.h>
#include <hip/hip_bf16.h>

typedef __hip_bfloat16 bf16;
typedef __attribute__((ext_vector_type(8))) short s16x8;
typedef __attribute__((ext_vector_type(4))) float f32x4;

#define DEV __device__ __forceinline__

DEV float b2f(bf16 v){ return __bfloat162float(v); }
DEV ushort f2bf(float f){ bf16 h = __float2bfloat16(f); return *reinterpret_cast<ushort*>(&h); }
DEV float bf2f(ushort u){ bf16 h; *reinterpret_cast<ushort*>(&h) = u; return __bfloat162float(h); }

constexpr int NPIX = 1024;
constexpr float EPSF = 1e-5f;
constexpr float LAMBDA_INIT_F = 0.3555090675909693f;
constexpr float ONE_M_LI     = 0.6444909324090307f;
constexpr float ATT_SCALE    = 0.17677669529663687f;

// workspace offsets (floats)
constexpr size_t OFF_XBUF  = 0;         // f32 [4][1024][256] residual, channel-last
constexpr size_t OFF_PARM  = 1048576;   // 17480 small params
constexpr size_t OFF_WBF   = 2120448;   // bf16 weights (1048576 ushorts)
constexpr size_t OFF_QT    = 2644736;   // QT/KT bf16 [2][4][8][1024][64]
constexpr size_t OFF_V16   = 4741888;   // V bf16 [4][512][1024]
constexpr size_t OFF_ATT   = 5790464;   // att bf16 [4][1024][512]; later chaout bf16
constexpr size_t OFF_BUF1  = 6839040;   // f32 [4][768][1024] qkv / ffn1 (channel-first)
constexpr size_t OFF_BUF2  = 9984768;   // f32 dw / gconv out (channel-first)
constexpr size_t OFF_SPART = 13130496;  // 262144 cha partial scores
constexpr size_t OFF_STATS = 13425408;  // LN1 partials sum[4][4096] sq[4][4096] (32768) + stats2 (8192) + stats3 (8192)
constexpr size_t OFF_EFF   = 13474560;  // folded params (2560) + lam(8)

struct PackArgs { const void* p[34]; };

DEV float rdin(const PackArgs& a, int i, int idx, int flag){
  return flag ? ((const float*)a.p[i])[idx] : b2f(((const bf16*)a.p[i])[idx]);
}

// block-local dtype detect: reads 256 halves of x; f32 random data decodes to
// huge bf16 values with per-element prob ~0.42 -> P(miss) ~ 0.58^256 ~ 0.
DEV int block_flag(const void* x, int* sh){
  const int t = threadIdx.x;
  if (t == 0) *sh = 0;
  __syncthreads();
  const float v = b2f(((const bf16*)x)[t]);
  if (!(fabsf(v) <= 1e6f)) atomicOr(sh, 1);
  __syncthreads();
  return *sh;
}

// ---------------- prep_merged: parm + Wbf + eff/lam + zero stats2/3 + xpose/LN1 ----------------
__global__ __launch_bounds__(256) void prep_merged_kernel(PackArgs args,
    float* __restrict__ parm, ushort* __restrict__ W, float* __restrict__ eff,
    float* __restrict__ stats, float* __restrict__ xb){
  __shared__ int shf;
  __shared__ float T[64][68];
  __shared__ float psum[64][4], psq[64][4];
  const int t = threadIdx.x;
  const int blk = blockIdx.x;
  const int flag = block_flag(args.p[0], &shf);
  if (blk < 69){
    const int g = blk*256 + t;
    if (g >= 17480) return;
    int src, loc;
    if      (g < 64)    { src = 10; loc = g; }
    else if (g < 72)    { src = 14; loc = g - 64; }
    else if (g < 6984)  { src = 16; loc = g - 72; }
    else if (g < 7496)  { src = 25; loc = g - 6984; }
    else if (g < 16712) { src = 30; loc = g - 7496; }
    else if (g < 17224) { src = 31; loc = g - 16712; }
    else                { src = 33; loc = g - 17224; }
    parm[g] = rdin(args, src, loc, flag);
  } else if (blk < 1093){
    const int g = (blk - 69)*1024 + t*4;     // < 1048576
    int src, loc;
    if      (g <  131072){ src = 3;  loc = g; }
    else if (g <  262144){ src = 4;  loc = g - 131072; }
    else if (g <  393216){ src = 5;  loc = g - 262144; }
    else if (g <  589824){ src = 15; loc = g - 393216; }
    else if (g <  720896){ src = 11; loc = g - 589824; }
    else if (g <  786432){ src = 17; loc = g - 720896; }
    else if (g <  917504){ src = 24; loc = g - 786432; }
    else                 { src = 32; loc = g - 917504; }
    ushort4 o;
    if (flag){
      const float4 v = *(const float4*)((const float*)args.p[src] + loc);
      o = make_ushort4(f2bf(v.x), f2bf(v.y), f2bf(v.z), f2bf(v.w));
    } else {
      o = *(const ushort4*)((const ushort*)args.p[src] + loc);
    }
    *(ushort4*)&W[g] = o;
  } else if (blk == 1093){
    eff[t]      = rdin(args,1,t,flag);  eff[256+t] = rdin(args,2,t,flag);
    eff[512+t]  = rdin(args,12,t,flag); eff[768+t] = rdin(args,13,t,flag);
    const float s1 = rdin(args,20,t,flag) * rsqrtf(rdin(args,23,t,flag) + EPSF);
    eff[1024+t] = rdin(args,18,t,flag) * s1;
    eff[1280+t] = (rdin(args,19,t,flag) - rdin(args,22,t,flag)) * s1 + rdin(args,21,t,flag);
    for (int c = t; c < 512; c += 256){
      const float sc = rdin(args,26,c,flag) * rsqrtf(rdin(args,29,c,flag) + EPSF);
      eff[1536+c] = sc;
      eff[2048+c] = rdin(args,27,c,flag) - rdin(args,28,c,flag)*sc;
    }
    if (t < 8){
      float e1 = 0.f, e2 = 0.f;
      for (int i = 0; i < 32; i++){
        e1 += rdin(args,6,t*32+i,flag) * rdin(args,7,t*32+i,flag);
        e2 += rdin(args,8,t*32+i,flag) * rdin(args,9,t*32+i,flag);
      }
      eff[2560+t] = __expf(e1) - __expf(e2) + LAMBDA_INIT_F;
    }
    // zero stats2 + stats3 raw accumulators (16384 floats at stats+32768)
    for (int i = t*4; i < 16384; i += 1024)
      *(float4*)&stats[32768 + i] = make_float4(0.f,0.f,0.f,0.f);
  } else {
    // blk 1094..1349: xpose x [b][c][n] -> xbuf [b][n][c] + LN1 partial stats (slot ct)
    const int bi = blk - 1094;
    const int nt = (bi & 15)*64, ct_i = (bi >> 4) & 3, b = bi >> 6;
    const int ct = ct_i*64;
    { const int c_ = t >> 2, nq = t & 3;
      const size_t base = ((size_t)b*256 + ct + c_)*1024 + nt + nq*16;
      float tmp[16];
      if (flag){
        #pragma unroll
        for (int j = 0; j < 4; j++){
          const float4 v = *(const float4*)((const float*)args.p[0] + base + j*4);
          tmp[j*4+0]=v.x; tmp[j*4+1]=v.y; tmp[j*4+2]=v.z; tmp[j*4+3]=v.w;
        }
      } else {
        const ushort* xh = (const ushort*)args.p[0] + base;
        #pragma unroll
        for (int j = 0; j < 2; j++){
          uint4 u = *(const uint4*)(xh + j*8);
          const ushort* us = (const ushort*)&u;
          #pragma unroll
          for (int k = 0; k < 8; k++) tmp[j*8+k] = bf2f(us[k]);
        }
      }
      #pragma unroll
      for (int j = 0; j < 4; j++)
        *(float4*)&T[c_][nq*16 + j*4] = make_float4(tmp[j*4],tmp[j*4+1],tmp[j*4+2],tmp[j*4+3]);
    }
    __syncthreads();
    { const int n_ = t >> 2, cq = t & 3;
      float s = 0.f, q = 0.f;
      float tmp[16];
      #pragma unroll
      for (int i = 0; i < 16; i++){
        const float v = T[cq*16 + i][n_];
        tmp[i] = v; s += v; q += v*v;
      }
      #pragma unroll
      for (int j = 0; j < 4; j++)
        *(float4*)&xb[((size_t)b*NPIX + nt + n_)*256 + ct + cq*16 + j*4] =
            make_float4(tmp[j*4],tmp[j*4+1],tmp[j*4+2],tmp[j*4+3]);
      psum[n_][cq] = s; psq[n_][cq] = q;
    }
    __syncthreads();
    if (t < 64){
      const float s = psum[t][0]+psum[t][1]+psum[t][2]+psum[t][3];
      const float q = psq[t][0]+psq[t][1]+psq[t][2]+psq[t][3];
      stats[ct_i*4096 + (size_t)b*NPIX + nt + t] = s;
      stats[16384 + ct_i*4096 + (size_t)b*NPIX + nt + t] = q;
    }
  }
}

// ---------------- unified MFMA GEMM ----------------
// IN: 0 = f32 [b][n][Cin] + LN (LNP: 4 partial slots, else raw); 1 = f32 [b][c][n]; 2 = bf16 [b][n][Cin]
// EPI: 0 = QKV special; 1 = f32 [n][c] +res (opt STATS); 2 = f32 [c][n] (+bias)(+bn2); 3 = final d_out
template<int INM, int EPIM, bool BIAS, bool BN2F, bool STATS, bool LNP>
__global__ __launch_bounds__(256) void gemm_kernel(
    const float* __restrict__ Xf, const ushort* __restrict__ Xb, const ushort* __restrict__ W,
    const float* __restrict__ bias, const float* __restrict__ mu, const float* __restrict__ rstd,
    const float* __restrict__ effw, const float* __restrict__ effb,
    const float* __restrict__ s2, const float* __restrict__ t2,
    const float* __restrict__ res, void* __restrict__ out,
    ushort* __restrict__ qt, ushort* __restrict__ v16,
    float* __restrict__ gstats,
    int Cin, const void* __restrict__ xsrc)
{
  __shared__ ushort Xt[64][72];
  __shared__ int shf;
  const int t = threadIdx.x;
  int fl = 0;
  if (EPIM == 3) fl = block_flag(xsrc, &shf);
  const int nb = blockIdx.x*64, ob = blockIdx.y*64, b = blockIdx.z;
  const int lane = t & 63, w = t >> 6;
  const int wR = w >> 1, wC = w & 1;
  const int l15 = lane & 15, g = lane >> 4;
  const int tn = t & 63, tc4 = t >> 6;
  const f32x4 z4 = {0.f,0.f,0.f,0.f};
  f32x4 acc[2][2] = {{z4,z4},{z4,z4}};

  float m_ = 0.f, r_ = 1.f;
  if (INM == 0){
    const int n_ = t >> 2;
    const size_t ix = (size_t)b*NPIX + nb + n_;
    float sv, qv;
    if (LNP){
      sv = mu[ix] + mu[4096 + ix] + mu[8192 + ix] + mu[12288 + ix];
      qv = rstd[ix] + rstd[4096 + ix] + rstd[8192 + ix] + rstd[12288 + ix];
    } else {
      sv = mu[ix]; qv = rstd[ix];
    }
    m_ = sv * (1.f/256.f);
    r_ = rsqrtf(fmaxf(qv*(1.f/256.f) - m_*m_, 0.f) + EPSF);
  }

  for (int kb = 0; kb < Cin; kb += 64){
    if (INM == 2){
      const ushort* src = Xb + ((size_t)b*NPIX + nb + tn)*Cin + kb + tc4*16;
      *(uint4*)&Xt[tn][tc4*16]   = *(const uint4*)src;
      *(uint4*)&Xt[tn][tc4*16+8] = *(const uint4*)(src+8);
    } else if (INM == 0){
      const int n_ = t >> 2, cq = t & 3;
      const float* src = Xf + ((size_t)b*NPIX + nb + n_)*Cin + kb + cq*16;
      float f[16];
      #pragma unroll
      for (int j = 0; j < 4; j++){
        const float4 v = *(const float4*)(src + j*4);
        f[j*4+0]=v.x; f[j*4+1]=v.y; f[j*4+2]=v.z; f[j*4+3]=v.w;
      }
      ushort tmp[16];
      #pragma unroll
      for (int i = 0; i < 16; i++){
        const int c = kb + cq*16 + i;
        tmp[i] = f2bf((f[i] - m_)*r_*effw[c] + effb[c]);
      }
      *(uint4*)&Xt[n_][cq*16]   = *(uint4*)&tmp[0];
      *(uint4*)&Xt[n_][cq*16+8] = *(uint4*)&tmp[8];
    } else {
      ushort tmp[16];
      #pragma unroll
      for (int i = 0; i < 16; i++){
        const int c = kb + tc4*16 + i;
        tmp[i] = f2bf(Xf[((size_t)b*Cin + c)*NPIX + nb + tn]);
      }
      *(uint4*)&Xt[tn][tc4*16]   = *(uint4*)&tmp[0];
      *(uint4*)&Xt[tn][tc4*16+8] = *(uint4*)&tmp[8];
    }
    __syncthreads();
    #pragma unroll
    for (int ks = 0; ks < 2; ks++){
      const s16x8 a0 = *(const s16x8*)&W[(size_t)(ob + wR*32 + l15)*Cin + kb + ks*32 + g*8];
      const s16x8 a1 = *(const s16x8*)&W[(size_t)(ob + wR*32 + 16 + l15)*Cin + kb + ks*32 + g*8];
      const s16x8 b0 = *(const s16x8*)&Xt[wC*32 + l15][ks*32 + g*8];
      const s16x8 b1 = *(const s16x8*)&Xt[wC*32 + 16 + l15][ks*32 + g*8];
      acc[0][0] = __builtin_amdgcn_mfma_f32_16x16x32_bf16(a0, b0, acc[0][0], 0,0,0);
      acc[0][1] = __builtin_amdgcn_mfma_f32_16x16x32_bf16(a0, b1, acc[0][1], 0,0,0);
      acc[1][0] = __builtin_amdgcn_mfma_f32_16x16x32_bf16(a1, b0, acc[1][0], 0,0,0);
      acc[1][1] = __builtin_amdgcn_mfma_f32_16x16x32_bf16(a1, b1, acc[1][1], 0,0,0);
    }
    __syncthreads();
  }

  const int Cout = gridDim.y*64;
  float sst[2] = {0.f, 0.f}, qst[2] = {0.f, 0.f};
  #pragma unroll
  for (int fr = 0; fr < 2; fr++){
    #pragma unroll
    for (int fc = 0; fc < 2; fc++){
      const int o = ob + wR*32 + fr*16 + 4*g;
      const int n = nb + wC*32 + fc*16 + l15;
      const f32x4 v = acc[fr][fc];
      if (EPIM == 0){
        if (ob < 1024){
          const int qk = o >> 9, h = (o >> 6) & 7, d = o & 63;
          ushort4 pk = make_ushort4(f2bf(v[0]), f2bf(v[1]), f2bf(v[2]), f2bf(v[3]));
          ushort* dst = qt + ((((size_t)qk*4 + b)*8 + h)*NPIX + n)*64 + d;
          *(ushort4*)dst = pk;
        } else {
          const int c = o - 1024;
          #pragma unroll
          for (int r = 0; r < 4; r++)
            v16[((size_t)b*512 + c + r)*NPIX + n] = f2bf(v[r]);
        }
      } else if (EPIM == 1){
        const size_t row = ((size_t)b*NPIX + n)*Cout + o;
        const float4 r4 = *(const float4*)&res[row];
        float vals[4];
        #pragma unroll
        for (int r = 0; r < 4; r++){
          float val = v[r];
          if (BIAS) val += bias[o+r];
          if (BN2F) val = val*s2[o+r] + t2[o+r];
          vals[r] = val + ((const float*)&r4)[r];
        }
        *(float4*)&((float*)out)[row] = make_float4(vals[0],vals[1],vals[2],vals[3]);
        if (STATS){
          sst[fc] += vals[0]+vals[1]+vals[2]+vals[3];
          qst[fc] += vals[0]*vals[0]+vals[1]*vals[1]+vals[2]*vals[2]+vals[3]*vals[3];
        }
      } else if (EPIM == 2){
        #pragma unroll
        for (int r = 0; r < 4; r++){
          float val = v[r];
          if (BIAS) val += bias[o + r];
          if (BN2F) val = val*s2[o+r] + t2[o+r];
          ((float*)out)[((size_t)b*Cout + o + r)*NPIX + n] = val;
        }
      } else {
        const float4 r4 = *(const float4*)&res[((size_t)b*NPIX + n)*256 + o];
        #pragma unroll
        for (int r = 0; r < 4; r++){
          float val = v[r] + ((const float*)&r4)[r];
          if (BIAS) val += bias[o+r];
          const size_t row = ((size_t)b*256 + o + r)*NPIX + n;
          if (fl) ((float*)out)[row] = val;
          else    ((ushort*)out)[row] = f2bf(val);
        }
      }
    }
  }
  if (STATS){
    float* sacc = (float*)&Xt[0][0];
    if (t < 128) sacc[t] = 0.f;
    __syncthreads();
    #pragma unroll
    for (int fc = 0; fc < 2; fc++){
      const int nl = wC*32 + fc*16 + l15;
      atomicAdd(&sacc[nl*2+0], sst[fc]);
      atomicAdd(&sacc[nl*2+1], qst[fc]);
    }
    __syncthreads();
    if (t < 64){
      atomicAdd(&gstats[(size_t)b*NPIX + nb + t],        sacc[t*2+0]);
      atomicAdd(&gstats[4096 + (size_t)b*NPIX + nb + t], sacc[t*2+1]);
    }
  }
}

// ---------------- MFMA differential attention, LDS-staged K/V ----------------
__global__ __launch_bounds__(256) void attn_kernel(
    const ushort* __restrict__ QT, const ushort* __restrict__ V16,
    const float* __restrict__ rms, const float* __restrict__ lamArr,
    ushort* __restrict__ att)
{
  __shared__ ushort Ks[2][4096];
  __shared__ ushort Vs[2][4096];
  const int t = threadIdx.x;
  const int lane = t & 63, w = t >> 6;
  const int l15 = lane & 15, g = lane >> 4;
  const int qt = blockIdx.x, h = blockIdx.y, b = blockIdx.z;
  const int qsub = qt*64 + w*16;
  const ushort* Qb = QT + ((size_t)b*8 + h)*NPIX*64;
  const ushort* Kb = QT + ((size_t)(4 + b)*8 + h)*NPIX*64;
  const ushort* Vb = V16 + ((size_t)b*512 + h*64)*NPIX;

  const int c0row = t >> 3, c0col = t & 7;
  const int c1row = (t + 256) >> 3, c1col = t & 7;
  const int sw0 = (c0col ^ (c0row & 7))*8;
  const int sw1 = (c1col ^ (c1row & 7))*8;

  s16x8 bq[2];
  #pragma unroll
  for (int hx = 0; hx < 2; hx++)
    bq[hx] = *(const s16x8*)&Qb[(size_t)(qsub + l15)*64 + 32*hx + 8*g];
  const float lam = lamArr[h];

  const f32x4 z4 = {0.f,0.f,0.f,0.f};
  f32x4 o0[4] = {z4,z4,z4,z4};
  f32x4 o1[4] = {z4,z4,z4,z4};
  float z[2] = {0.f, 0.f};

  uint4 kra = *(const uint4*)&Kb[(size_t)c0row*64 + c0col*8];
  uint4 krb = *(const uint4*)&Kb[(size_t)c1row*64 + c1col*8];
  uint4 vra = *(const uint4*)&Vb[(size_t)c0row*NPIX + c0col*8];
  uint4 vrb = *(const uint4*)&Vb[(size_t)c1row*NPIX + c1col*8];
  *(uint4*)&Ks[0][c0row*64 + sw0] = kra;
  *(uint4*)&Ks[0][c1row*64 + sw1] = krb;
  *(uint4*)&Vs[0][c0row*64 + sw0] = vra;
  *(uint4*)&Vs[0][c1row*64 + sw1] = vrb;
  kra = *(const uint4*)&Kb[(size_t)(64 + c0row)*64 + c0col*8];
  krb = *(const uint4*)&Kb[(size_t)(64 + c1row)*64 + c1col*8];
  vra = *(const uint4*)&Vb[(size_t)c0row*NPIX + 64 + c0col*8];
  vrb = *(const uint4*)&Vb[(size_t)c1row*NPIX + 64 + c1col*8];
  __syncthreads();

  #pragma unroll 1
  for (int it = 0; it < 16; it++){
    const int cur = it & 1;
    const ushort* Kc = &Ks[cur][0];
    const ushort* Vc = &Vs[cur][0];

    f32x4 s[2][4];
    #pragma unroll
    for (int fr = 0; fr < 4; fr++){
      const int row = fr*16 + l15;
      const int rx = (row & 7)*8;
      #pragma unroll
      for (int hx = 0; hx < 2; hx++){
        const s16x8 ak = *(const s16x8*)&Kc[row*64 + ((hx*32 + 8*g) ^ rx)];
        s[hx][fr] = __builtin_amdgcn_mfma_f32_16x16x32_bf16(ak, bq[hx], z4, 0,0,0);
      }
    }
    s16x8 pa[2][2];
    #pragma unroll
    for (int hx = 0; hx < 2; hx++){
      #pragma unroll
      for (int ms = 0; ms < 2; ms++){
        ushort tmp[8];
        #pragma unroll
        for (int fr2 = 0; fr2 < 2; fr2++)
          #pragma unroll
          for (int r = 0; r < 4; r++){
            const float e = __expf(s[hx][ms*2 + fr2][r] * ATT_SCALE);
            z[hx] += e;
            tmp[fr2*4 + r] = f2bf(e);
          }
        pa[hx][ms] = *(s16x8*)tmp;
      }
    }
    __builtin_amdgcn_s_setprio(1);
    #pragma unroll
    for (int ms = 0; ms < 2; ms++){
      #pragma unroll
      for (int dc = 0; dc < 4; dc++){
        const int row = dc*16 + l15;
        const int r7 = row & 7;
        const int elo = ms*32 + 4*g;
        const int eloswz = ((((elo >> 3) ^ r7) << 3) | (elo & 7));
        const int ehi = elo + 16;
        const int ehiswz = ((((ehi >> 3) ^ r7) << 3) | (ehi & 7));
        const uint2 lo = *(const uint2*)&Vc[row*64 + eloswz];
        const uint2 hi = *(const uint2*)&Vc[row*64 + ehiswz];
        union { uint u[4]; s16x8 v; } bv;
        bv.u[0] = lo.x; bv.u[1] = lo.y; bv.u[2] = hi.x; bv.u[3] = hi.y;
        o0[dc] = __builtin_amdgcn_mfma_f32_16x16x32_bf16(pa[0][ms], bv.v, o0[dc], 0,0,0);
        o1[dc] = __builtin_amdgcn_mfma_f32_16x16x32_bf16(pa[1][ms], bv.v, o1[dc], 0,0,0);
      }
    }
    __builtin_amdgcn_s_setprio(0);

    if (it < 15){
      const int nxt = cur ^ 1;
      *(uint4*)&Ks[nxt][c0row*64 + sw0] = kra;
      *(uint4*)&Ks[nxt][c1row*64 + sw1] = krb;
      *(uint4*)&Vs[nxt][c0row*64 + sw0] = vra;
      *(uint4*)&Vs[nxt][c1row*64 + sw1] = vrb;
      if (it < 14){
        const int m0 = (it + 2)*64;
        kra = *(const uint4*)&Kb[(size_t)(m0 + c0row)*64 + c0col*8];
        krb = *(const uint4*)&Kb[(size_t)(m0 + c1row)*64 + c1col*8];
        vra = *(const uint4*)&Vb[(size_t)c0row*NPIX + m0 + c0col*8];
        vrb = *(const uint4*)&Vb[(size_t)c1row*NPIX + m0 + c1col*8];
      }
    }
    __syncthreads();
  }

  #pragma unroll
  for (int hx = 0; hx < 2; hx++){
    z[hx] += __shfl_xor(z[hx], 16);
    z[hx] += __shfl_xor(z[hx], 32);
  }
  float zi0[4], zi1[4];
  #pragma unroll
  for (int r = 0; r < 4; r++){
    zi0[r] = 1.f / __shfl(z[0], 4*g + r);
    zi1[r] = 1.f / __shfl(z[1], 4*g + r);
  }
  float val[4][4];
  float ss[4] = {0.f,0.f,0.f,0.f};
  #pragma unroll
  for (int dc = 0; dc < 4; dc++)
    #pragma unroll
    for (int r = 0; r < 4; r++){
      const float vv = o0[dc][r]*zi0[r] - lam*o1[dc][r]*zi1[r];
      val[dc][r] = vv; ss[r] += vv*vv;
    }
  #pragma unroll
  for (int r = 0; r < 4; r++){
    ss[r] += __shfl_xor(ss[r], 1);
    ss[r] += __shfl_xor(ss[r], 2);
    ss[r] += __shfl_xor(ss[r], 4);
    ss[r] += __shfl_xor(ss[r], 8);
  }
  float rinv[4];
  #pragma unroll
  for (int r = 0; r < 4; r++) rinv[r] = ONE_M_LI * rsqrtf(ss[r]*(1.f/64.f) + EPSF);
  #pragma unroll
  for (int dc = 0; dc < 4; dc++){
    const float rs = rms[dc*16 + l15];
    #pragma unroll
    for (int r = 0; r < 4; r++){
      const int n = qsub + 4*g + r;
      att[((size_t)b*NPIX + n)*512 + h*64 + dc*16 + l15] = f2bf(val[dc][r]*rinv[r]*rs);
    }
  }
}

// ---------------- fused depthwise 3x3 + L2-norm (block = plane) ----------------
__global__ __launch_bounds__(256) void dwl2_kernel(const float* __restrict__ in,
    const float* __restrict__ wdw, float* __restrict__ out){
  __shared__ float tile[1024];
  __shared__ float wsum[4];
  const int p = blockIdx.x;                 // b*768 + c
  const int c = p % 768;
  const int t = threadIdx.x;
  const float* ip = in + (size_t)p*1024;
  *(float4*)&tile[t*4] = *(const float4*)&ip[t*4];
  float wv[9];
  #pragma unroll
  for (int i = 0; i < 9; i++) wv[i] = wdw[c*9+i];
  __syncthreads();
  float o[4]; float ssq = 0.f;
  #pragma unroll
  for (int j = 0; j < 4; j++){
    const int px = t*4 + j, x = px & 31, y = px >> 5;
    float s = 0.f;
    #pragma unroll
    for (int ky = 0; ky < 3; ky++){
      const int yy = y + ky - 1;
      if (yy < 0 || yy > 31) continue;
      #pragma unroll
      for (int kx = 0; kx < 3; kx++){
        const int xx = x + kx - 1;
        if (xx < 0 || xx > 31) continue;
        s = fmaf(tile[yy*32+xx], wv[ky*3+kx], s);
      }
    }
    o[j] = s; ssq += s*s;
  }
  for (int off = 32; off; off >>= 1) ssq += __shfl_down(ssq, off);
  if ((t & 63) == 0) wsum[t >> 6] = ssq;
  __syncthreads();
  float inv = 1.f;
  if (c < 512){
    const float tot = wsum[0]+wsum[1]+wsum[2]+wsum[3];
    inv = 1.f / fmaxf(sqrtf(tot), 1e-12f);
  }
  *(float4*)&out[(size_t)p*1024 + t*4] = make_float4(o[0]*inv, o[1]*inv, o[2]*inv, o[3]*inv);
}

// ---------------- CHA partial scores ----------------
__global__ __launch_bounds__(256) void cha_scores_kernel(const float* __restrict__ qk,
                                                         float* __restrict__ spart){
  __shared__ float qs[32][129];
  __shared__ float ks[32][129];
  const int t = threadIdx.x;
  const int nb = blockIdx.x*128;
  const int bh = blockIdx.y, b = bh >> 3, h = bh & 7;
  const size_t qbase = ((size_t)b*768 + h*32)*NPIX + nb;
  const size_t kbase = qbase + (size_t)256*NPIX;
  { const int c = t >> 3, n0 = (t & 7)*16;
    #pragma unroll
    for (int j = 0; j < 4; j++){
      const float4 vq = *(const float4*)&qk[qbase + (size_t)c*NPIX + n0 + j*4];
      const float4 vk = *(const float4*)&qk[kbase + (size_t)c*NPIX + n0 + j*4];
      qs[c][n0+j*4+0]=vq.x; qs[c][n0+j*4+1]=vq.y; qs[c][n0+j*4+2]=vq.z; qs[c][n0+j*4+3]=vq.w;
      ks[c][n0+j*4+0]=vk.x; ks[c][n0+j*4+1]=vk.y; ks[c][n0+j*4+2]=vk.z; ks[c][n0+j*4+3]=vk.w;
    } }
  __syncthreads();
  const int c = t & 31, dg = t >> 5;
  float acc[4] = {};
  for (int nn = 0; nn < 128; nn++){
    const float qv = qs[c][nn];
    #pragma unroll
    for (int j = 0; j < 4; j++) acc[j] = fmaf(qv, ks[dg*4+j][nn], acc[j]);
  }
  float* sp = spart + ((size_t)bh*8 + blockIdx.x)*1024 + c*32 + dg*4;
  #pragma unroll
  for (int j = 0; j < 4; j++) sp[j] = acc[j];
}

// ---------------- CHA softmax + PV -> chaout bf16 [b][n][256] ----------------
__global__ __launch_bounds__(256) void cha_pv_kernel(const float* __restrict__ spart,
    const float* __restrict__ tempP, const float* __restrict__ qkv, ushort* __restrict__ out16){
  __shared__ float Ps[32][33];
  const int t = threadIdx.x;
  const int bh = blockIdx.y, b = bh >> 3, h = bh & 7;
  const int nb = blockIdx.x*64;
  const float tf = tempP[h];
  for (int p = t; p < 1024; p += 256){
    float s = 0.f;
    #pragma unroll
    for (int ch = 0; ch < 8; ch++) s += spart[((size_t)bh*8 + ch)*1024 + p];
    Ps[p >> 5][p & 31] = s * tf;
  }
  __syncthreads();
  if (t < 32){
    float mx = -1e30f;
    #pragma unroll
    for (int d = 0; d < 32; d++) mx = fmaxf(mx, Ps[t][d]);
    float sum = 0.f; float e[32];
    #pragma unroll
    for (int d = 0; d < 32; d++){ e[d] = __expf(Ps[t][d]-mx); sum += e[d]; }
    const float inv = 1.f/sum;
    #pragma unroll
    for (int d = 0; d < 32; d++) Ps[t][d] = e[d]*inv;
  }
  __syncthreads();
  const int n = nb + (t & 63);
  const int cg = t >> 6;
  const size_t vbase = ((size_t)b*768 + 512 + h*32)*NPIX + n;
  float acc[8] = {};
  for (int d = 0; d < 32; d++){
    const float v = qkv[vbase + (size_t)d*NPIX];
    #pragma unroll
    for (int j = 0; j < 8; j++) acc[j] = fmaf(Ps[cg*8+j][d], v, acc[j]);
  }
  ushort o8[8];
  #pragma unroll
  for (int j = 0; j < 8; j++) o8[j] = f2bf(acc[j]);
  *(uint4*)&out16[((size_t)b*NPIX + n)*256 + h*32 + cg*8] = *(uint4*)o8;
}

// ---------------- FFN grouped 3x3 + bias + relu6, LDS-tiled ----------------
__global__ __launch_bounds__(256) void gconv_lds_kernel(const float* __restrict__ in,
    const float* __restrict__ w, const float* __restrict__ bias, float* __restrict__ out){
  __shared__ float tin[2][1024];
  const int p = blockIdx.x;                 // b*512 + o
  const int o = p & 511, b = p >> 9;
  const int t = threadIdx.x;
  const float* ip = in + ((size_t)b*512 + (o & ~1))*1024;
  *(float4*)&tin[0][t*4] = *(const float4*)&ip[t*4];
  *(float4*)&tin[1][t*4] = *(const float4*)&ip[1024 + t*4];
  float wv[18];
  #pragma unroll
  for (int i = 0; i < 18; i++) wv[i] = w[o*18 + i];
  const float bs = bias[o];
  __syncthreads();
  float res[4];
  #pragma unroll
  for (int j = 0; j < 4; j++){
    const int px = t*4 + j, x = px & 31, y = px >> 5;
    float s = bs;
    #pragma unroll
    for (int ci = 0; ci < 2; ci++){
      #pragma unroll
      for (int ky = 0; ky < 3; ky++){
        const int yy = y + ky - 1;
        if (yy < 0 || yy > 31) continue;
        #pragma unroll
        for (int kx = 0; kx < 3; kx++){
          const int xx = x + kx - 1;
          if (xx < 0 || xx > 31) continue;
          s = fmaf(tin[ci][yy*32+xx], wv[ci*9 + ky*3 + kx], s);
        }
      }
    }
    res[j] = fminf(fmaxf(s, 0.f), 6.f);
  }
  *(float4*)&out[(size_t)p*1024 + t*4] = make_float4(res[0], res[1], res[2], res[3]);
}

extern "C" void kernel_launch(void* const* d_in, const int* in_sizes, int n_in,
                              void* d_out, int out_size, void* d_ws, size_t ws_size,
                              hipStream_t stream)
{
  (void)in_sizes; (void)n_in; (void)out_size; (void)ws_size;

  float* ws    = (float*)d_ws;
  float* xbuf  = ws + OFF_XBUF;
  float* parm  = ws + OFF_PARM;
  ushort* Wbf  = (ushort*)(ws + OFF_WBF);
  ushort* QT   = (ushort*)(ws + OFF_QT);
  ushort* V16  = (ushort*)(ws + OFF_V16);
  ushort* att  = (ushort*)(ws + OFF_ATT);
  ushort* cha16= (ushort*)(ws + OFF_ATT);
  float* buf1  = ws + OFF_BUF1;
  float* buf2  = ws + OFF_BUF2;
  float* spart = ws + OFF_SPART;
  float* stats = ws + OFF_STATS;
  float* eff   = ws + OFF_EFF;

  PackArgs pa;
  for (int i = 0; i < 34; i++) pa.p[i] = d_in[i];
  prep_merged_kernel<<<1350, 256, 0, stream>>>(pa, parm, Wbf, eff, stats, xbuf);

  // ---- CDA ----
  gemm_kernel<0,0,false,false,false,true><<<dim3(16,24,4), 256, 0, stream>>>(
      xbuf, nullptr, Wbf, nullptr, stats, stats+16384, eff, eff+256,
      nullptr, nullptr, nullptr, nullptr, QT, V16, nullptr, 256, nullptr);
  attn_kernel<<<dim3(16,8,4), 256, 0, stream>>>(QT, V16, parm, eff+2560, att);
  gemm_kernel<2,1,false,false,true,false><<<dim3(16,4,4), 256, 0, stream>>>(
      nullptr, att, Wbf+589824, nullptr, nullptr, nullptr, nullptr, nullptr,
      nullptr, nullptr, xbuf, xbuf, nullptr, nullptr, stats+32768, 512, nullptr);

  // ---- CHA ----
  gemm_kernel<0,2,false,false,false,false><<<dim3(16,12,4), 256, 0, stream>>>(
      xbuf, nullptr, Wbf+393216, nullptr, stats+32768, stats+36864, eff+512, eff+768,
      nullptr, nullptr, nullptr, buf1, nullptr, nullptr, nullptr, 256, nullptr);
  dwl2_kernel<<<3072, 256, 0, stream>>>(buf1, parm + 72, buf2);
  cha_scores_kernel<<<dim3(8,32), 256, 0, stream>>>(buf2, spart);
  cha_pv_kernel<<<dim3(16,32), 256, 0, stream>>>(spart, parm + 64, buf2, cha16);
  gemm_kernel<2,1,false,false,true,false><<<dim3(16,4,4), 256, 0, stream>>>(
      nullptr, cha16, Wbf+720896, nullptr, nullptr, nullptr, nullptr, nullptr,
      nullptr, nullptr, xbuf, xbuf, nullptr, nullptr, stats+40960, 256, nullptr);

  // ---- FFN ----
  gemm_kernel<0,2,true,true,false,false><<<dim3(16,8,4), 256, 0, stream>>>(
      xbuf, nullptr, Wbf+786432, parm+6984, stats+40960, stats+45056, eff+1024, eff+1280,
      eff+1536, eff+2048, nullptr, buf1, nullptr, nullptr, nullptr, 256, nullptr);
  gconv_lds_kernel<<<2048, 256, 0, stream>>>(buf1, parm+7496, parm+16712, buf2);
  gemm_kernel<1,3,true,false,false,false><<<dim3(16,4,4), 256, 0, stream>>>(
      buf2, nullptr, Wbf+917504, parm+17224, nullptr, nullptr, nullptr, nullptr,
      nullptr, nullptr, xbuf, d_out, nullptr, nullptr, nullptr, 512, d_in[0]);
}